// Round 3
// baseline (1366.468 us; speedup 1.0000x reference)
//
#include <hip/hip_runtime.h>
#include <math.h>

#define PP 22
#define HH 64
#define NL 4
#define NE 462     // 22*21 directed edges
#define NTILE 29   // ceil(462/16) edge tiles of M=16
#define SST 68     // float stride for node-feature rows (bank-decorrelated)
#define EST 72     // uint stride for packed bf16 hi|lo tiles

typedef __attribute__((ext_vector_type(8))) short bf16x8;
typedef __attribute__((ext_vector_type(4))) float f32x4;

#define MFMA(A, B, C) __builtin_amdgcn_mfma_f32_16x16x32_bf16(A, B, C, 0, 0, 0)

__device__ __forceinline__ float silu_f(float v) { return v / (1.0f + __expf(-v)); }

__device__ __forceinline__ unsigned short f2bf(float x) {
    unsigned int u = __float_as_uint(x);
    u += 0x7fffu + ((u >> 16) & 1u);
    return (unsigned short)(u >> 16);
}
__device__ __forceinline__ float bf2f(unsigned short h) {
    return __uint_as_float(((unsigned int)h) << 16);
}

#define LD8(dst, PTR) { \
    float4 _a = *(const float4*)(PTR); float4 _b = *(const float4*)((PTR) + 4); \
    dst[0]=_a.x; dst[1]=_a.y; dst[2]=_a.z; dst[3]=_a.w; \
    dst[4]=_b.x; dst[5]=_b.y; dst[6]=_b.z; dst[7]=_b.w; }

// ---------------------------------------------------------------------------
// Weight prep: 8 mats per layer -> hi/lo bf16 B-fragment blocks.
// mat: 0=W1a 1=W1b 2=W2 3=CM1 4=CC1 5=NW1a 6=NW1b 7=NW2
// block = ((l*8+mat)*2+kt)*4+nt, 1024 ushorts: [0..511] hi, [512..1023] lo
// frag element: lane*8+j -> M[kt*32+(lane>>4)*8+j][nt*16+(lane&15)]
// ---------------------------------------------------------------------------
__global__ __launch_bounds__(64) void prep_w(
    const float* __restrict__ edge_w1, const float* __restrict__ edge_w2,
    const float* __restrict__ cm_w1, const float* __restrict__ cc_w1,
    const float* __restrict__ node_w1, const float* __restrict__ node_w2,
    unsigned short* __restrict__ ws)
{
    int blk = blockIdx.x;
    int nt = blk & 3, kt = (blk >> 2) & 1, mat = (blk >> 3) & 7, l = blk >> 6;
    const float* src;
    switch (mat) {
        case 0: src = edge_w1 + l * 130 * HH; break;
        case 1: src = edge_w1 + l * 130 * HH + 64 * HH; break;
        case 2: src = edge_w2 + l * HH * HH; break;
        case 3: src = cm_w1   + l * HH * HH; break;
        case 4: src = cc_w1   + l * HH * HH; break;
        case 5: src = node_w1 + l * 128 * HH; break;
        case 6: src = node_w1 + l * 128 * HH + 64 * HH; break;
        default: src = node_w2 + l * HH * HH; break;
    }
    int lane = threadIdx.x;
    int n  = nt * 16 + (lane & 15);
    int kb = kt * 32 + (lane >> 4) * 8;
    unsigned short* dh = ws + blk * 1024 + lane * 8;
#pragma unroll
    for (int j = 0; j < 8; ++j) {
        float v = src[(kb + j) * HH + n];
        unsigned short hi = f2bf(v);
        unsigned short lo = f2bf(v - bf2f(hi));
        dh[j]       = hi;
        dh[512 + j] = lo;
    }
}

// ---------------------------------------------------------------------------
// Main kernel: one graph per block, 512 threads (8 waves), ~75KB LDS.
// ---------------------------------------------------------------------------
__global__ __launch_bounds__(512, 4) void egnn_kernel(
    const float* __restrict__ input, const float* __restrict__ timev,
    const float* __restrict__ emb_w, const float* __restrict__ emb_b,
    const float* __restrict__ edge_w1, const float* __restrict__ edge_b1,
    const float* __restrict__ edge_b2,
    const float* __restrict__ node_b1, const float* __restrict__ node_b2,
    const float* __restrict__ cm_b1, const float* __restrict__ cm_w2,
    const float* __restrict__ cc_b1, const float* __restrict__ cc_w2,
    const unsigned short* __restrict__ wfr,
    float* __restrict__ out)
{
    const int g    = blockIdx.x;
    const int tid  = threadIdx.x;
    const int w    = tid >> 6;
    const int lane = tid & 63;
    const int n0   = lane & 15;
    const int kg   = lane >> 4;
    const int mtile = w >> 2;      // node-phase combo: M-tile 0/1
    const int ntw   = w & 3;       // node-phase combo: N-tile 0..3

    __shared__ float sApre[PP][SST], sBpre[PP][SST];
    __shared__ float sh[PP][SST], sSeg[PP][SST];
    __shared__ float srad[NE], sea[NE];
    __shared__ float scd[NE][3], scr[NE][3];
    __shared__ float sx[PP][3], sx0[PP][3], sTr[PP][4];
    __shared__ float sW128[HH], sW129[HH];
    __shared__ float smean[3];
    __shared__ __align__(16) unsigned int sEF[8][16 * EST];   // per-wave packed tiles
    unsigned int* sM = &sEF[0][0];                            // aliased in node phase

    // ---- init ----
    if (tid < PP * 3) {
        float v = input[g * (PP * 3) + tid];
        sx0[tid / 3][tid % 3] = v;
        sx [tid / 3][tid % 3] = v;
    }
    {
        float tg = timev[g];
        for (int i = w; i < PP; i += 8)
            sh[i][lane] = emb_w[i * HH + lane] + tg * emb_w[PP * HH + lane] + emb_b[lane];
    }
    for (int idx = tid; idx < PP * SST; idx += 512) (&sSeg[0][0])[idx] = 0.f;
    if (tid < PP * 4) (&sTr[0][0])[tid] = 0.f;
    __syncthreads();
    if (tid < NE) {
        int a = tid / 21, r = tid % 21;
        int b = (r < a) ? r : r + 1;
        float dx = sx0[a][0] - sx0[b][0];
        float dy = sx0[a][1] - sx0[b][1];
        float dz = sx0[a][2] - sx0[b][2];
        sea[tid] = dx * dx + dy * dy + dz * dz;
    }

    for (int l = 0; l < NL; ++l) {
        const unsigned short* wfl = wfr + (size_t)l * 65536;

        // ---- [A] geometry from current x ----
        if (tid < NE) {
            int a = tid / 21, r = tid % 21;
            int b = (r < a) ? r : r + 1;
            float ax = sx[a][0], ay = sx[a][1], az = sx[a][2];
            float bx = sx[b][0], by = sx[b][1], bz = sx[b][2];
            float dx = ax - bx, dy = ay - by, dz = az - bz;
            float rad = dx * dx + dy * dy + dz * dz;
            srad[tid] = rad;
            float inv = 1.0f / (sqrtf(rad + 1e-8f) + 1.0f);
            scd[tid][0] = dx * inv; scd[tid][1] = dy * inv; scd[tid][2] = dz * inv;
            float cx = ay * bz - az * by;
            float cy = az * bx - ax * bz;
            float cz = ax * by - ay * bx;
            float cn = 1.0f / (sqrtf(cx * cx + cy * cy + cz * cz + 1e-8f) + 1.0f);
            scr[tid][0] = cx * cn; scr[tid][1] = cy * cn; scr[tid][2] = cz * cn;
        }
        // ---- [B] W1 rows 128/129 ----
        if (tid < HH)          sW128[tid]      = edge_w1[(l * 130 + 128) * HH + tid];
        else if (tid < 2 * HH) sW129[tid - HH] = edge_w1[(l * 130 + 129) * HH + tid - HH];

        // ---- [C] Apre/Bpre via MFMA: combo (mtile, ntw) per wave ----
        {
            int node = mtile * 16 + n0;
            int crow = node < PP ? node : 0;
            bool vn = node < PP;
            bf16x8 hhi[2], hlo[2];
#pragma unroll
            for (int kt = 0; kt < 2; ++kt) {
                float vv[8];
                LD8(vv, &sh[crow][kt * 32 + kg * 8]);
#pragma unroll
                for (int j = 0; j < 8; ++j) {
                    float z = vn ? vv[j] : 0.f;
                    unsigned short hi = f2bf(z);
                    hhi[kt][j] = (short)hi;
                    hlo[kt][j] = (short)f2bf(z - bf2f(hi));
                }
            }
            f32x4 accA = (f32x4){0.f,0.f,0.f,0.f};
            f32x4 accB = (f32x4){0.f,0.f,0.f,0.f};
#pragma unroll
            for (int kt = 0; kt < 2; ++kt) {
                const unsigned short* p0 = wfl + (0 * 8 + kt * 4 + ntw) * 1024 + lane * 8;
                bf16x8 bhi = *(const bf16x8*)p0, blo = *(const bf16x8*)(p0 + 512);
                accA = MFMA(hhi[kt], bhi, accA);
                accA = MFMA(hlo[kt], bhi, accA);
                accA = MFMA(hhi[kt], blo, accA);
                const unsigned short* p1 = wfl + (1 * 8 + kt * 4 + ntw) * 1024 + lane * 8;
                bf16x8 chi = *(const bf16x8*)p1, clo = *(const bf16x8*)(p1 + 512);
                accB = MFMA(hhi[kt], chi, accB);
                accB = MFMA(hlo[kt], chi, accB);
                accB = MFMA(hhi[kt], clo, accB);
            }
            int col = ntw * 16 + n0;
            float b1v = edge_b1[l * HH + col];
#pragma unroll
            for (int q = 0; q < 4; ++q) {
                int m = mtile * 16 + kg * 4 + q;
                if (m < PP) {
                    sApre[m][col] = accA[q] + b1v;
                    sBpre[m][col] = accB[q];
                }
            }
        }
        // per-lane layer constants
        float b2r[4], cmbr[4], ccbr[4], cm2r[4], cc2r[4];
#pragma unroll
        for (int nt = 0; nt < 4; ++nt) {
            int idx = l * HH + nt * 16 + n0;
            b2r[nt]  = edge_b2[idx];
            cmbr[nt] = cm_b1[idx];
            ccbr[nt] = cc_b1[idx];
            cm2r[nt] = cm_w2[idx];
            cc2r[nt] = cc_w2[idx];
        }
        __syncthreads();  // (1)

        // ================= [D] edge phase: edge-major tiles =================
        unsigned int* sEFw = &sEF[w][0];
        for (int j = w; j < NTILE; j += 8) {
            int e0 = j * 16;
            int e = e0 + n0;
            int ec = e < NE ? e : 0;
            int a = ec / 21, r = ec - a * 21;
            int b = (r < a) ? r : r + 1;
            float radv = srad[ec], eav = sea[ec];

            // A-frags: z1 = silu(Apre[a]+Bpre[b]+rad*w128+ea*w129)
            bf16x8 ahi[2], alo[2];
#pragma unroll
            for (int kt = 0; kt < 2; ++kt) {
                int base = kt * 32 + kg * 8;
                float av[8], bv[8], w8[8], w9[8];
                LD8(av, &sApre[a][base]);
                LD8(bv, &sBpre[b][base]);
                LD8(w8, &sW128[base]);
                LD8(w9, &sW129[base]);
#pragma unroll
                for (int j8 = 0; j8 < 8; ++j8) {
                    float z = av[j8] + bv[j8] + radv * w8[j8] + eav * w9[j8];
                    z = silu_f(z);
                    unsigned short hi = f2bf(z);
                    ahi[kt][j8] = (short)hi;
                    alo[kt][j8] = (short)f2bf(z - bf2f(hi));
                }
            }

            // E2: EF = silu(z1@W2+b2); seg atomics; pack to sEFw
#pragma unroll
            for (int nt = 0; nt < 4; ++nt) {
                f32x4 acc = (f32x4){0.f,0.f,0.f,0.f};
#pragma unroll
                for (int kt = 0; kt < 2; ++kt) {
                    const unsigned short* p = wfl + (2 * 8 + kt * 4 + nt) * 1024 + lane * 8;
                    bf16x8 bhi = *(const bf16x8*)p, blo = *(const bf16x8*)(p + 512);
                    acc = MFMA(ahi[kt], bhi, acc);
                    acc = MFMA(alo[kt], bhi, acc);
                    acc = MFMA(ahi[kt], blo, acc);
                }
                int col = nt * 16 + n0;
#pragma unroll
                for (int q = 0; q < 4; ++q) {
                    int erow = kg * 4 + q;
                    int gE = e0 + erow;
                    bool vr = gE < NE;
                    float v = silu_f(acc[q] + b2r[nt]);
                    v = vr ? v : 0.f;
                    if (vr) {
                        int an = gE / 21;
                        atomicAdd(&sSeg[an][col], v);
                    }
                    unsigned short hi = f2bf(v);
                    unsigned short lo = f2bf(v - bf2f(hi));
                    sEFw[erow * EST + col] = (unsigned)hi | ((unsigned)lo << 16);
                }
            }

            // E3 A-frags from sEFw (per-wave ds ops are in-order)
            bf16x8 ehi[2], elo[2];
#pragma unroll
            for (int kt = 0; kt < 2; ++kt) {
                const unsigned int* p = &sEFw[n0 * EST + kt * 32 + kg * 8];
                uint4 u0 = *(const uint4*)p;
                uint4 u1 = *(const uint4*)(p + 4);
                unsigned uu[8] = {u0.x, u0.y, u0.z, u0.w, u1.x, u1.y, u1.z, u1.w};
#pragma unroll
                for (int j8 = 0; j8 < 8; ++j8) {
                    ehi[kt][j8] = (short)(uu[j8] & 0xffffu);
                    elo[kt][j8] = (short)(uu[j8] >> 16);
                }
            }

            // E3: cm/cc heads
            float pm[4] = {0.f,0.f,0.f,0.f}, pc[4] = {0.f,0.f,0.f,0.f};
#pragma unroll
            for (int nt = 0; nt < 4; ++nt) {
                f32x4 am = (f32x4){0.f,0.f,0.f,0.f};
                f32x4 ac = (f32x4){0.f,0.f,0.f,0.f};
#pragma unroll
                for (int kt = 0; kt < 2; ++kt) {
                    const unsigned short* pmw = wfl + (3 * 8 + kt * 4 + nt) * 1024 + lane * 8;
                    const unsigned short* pcw = wfl + (4 * 8 + kt * 4 + nt) * 1024 + lane * 8;
                    bf16x8 mhi = *(const bf16x8*)pmw, mlo = *(const bf16x8*)(pmw + 512);
                    bf16x8 chi = *(const bf16x8*)pcw, clo = *(const bf16x8*)(pcw + 512);
                    am = MFMA(ehi[kt], mhi, am);
                    am = MFMA(elo[kt], mhi, am);
                    am = MFMA(ehi[kt], mlo, am);
                    ac = MFMA(ehi[kt], chi, ac);
                    ac = MFMA(elo[kt], chi, ac);
                    ac = MFMA(ehi[kt], clo, ac);
                }
#pragma unroll
                for (int q = 0; q < 4; ++q) {
                    pm[q] += silu_f(am[q] + cmbr[nt]) * cm2r[nt];
                    pc[q] += silu_f(ac[q] + ccbr[nt]) * cc2r[nt];
                }
            }
#pragma unroll
            for (int q = 0; q < 4; ++q) {
#pragma unroll
                for (int off = 1; off <= 8; off <<= 1) {
                    pm[q] += __shfl_xor(pm[q], off);
                    pc[q] += __shfl_xor(pc[q], off);
                }
            }
            if (n0 < 3) {
#pragma unroll
                for (int q = 0; q < 4; ++q) {
                    int gE = e0 + kg * 4 + q;
                    if (gE < NE) {
                        int a2 = gE / 21;
                        atomicAdd(&sTr[a2][n0], scd[gE][n0] * pm[q] + pc[q] * scr[gE][n0]);
                    }
                }
            }
        }
        __syncthreads();  // (2)

        // ================= [E] node MLP stage 1 -> sM ======================
        {
            int node = mtile * 16 + n0;
            int crow = node < PP ? node : 0;
            bool vn = node < PP;
            bf16x8 nhi[4], nlo[4];
#pragma unroll
            for (int kt = 0; kt < 4; ++kt) {
                float vv[8];
                const float* src = (kt < 2) ? &sh[crow][kt * 32 + kg * 8]
                                            : &sSeg[crow][(kt - 2) * 32 + kg * 8];
                LD8(vv, src);
#pragma unroll
                for (int j8 = 0; j8 < 8; ++j8) {
                    float z = vn ? vv[j8] : 0.f;
                    unsigned short hi = f2bf(z);
                    nhi[kt][j8] = (short)hi;
                    nlo[kt][j8] = (short)f2bf(z - bf2f(hi));
                }
            }
            f32x4 acc = (f32x4){0.f,0.f,0.f,0.f};
#pragma unroll
            for (int kt = 0; kt < 4; ++kt) {
                int mat = (kt < 2) ? 5 : 6;
                int ktt = kt & 1;
                const unsigned short* p = wfl + (mat * 8 + ktt * 4 + ntw) * 1024 + lane * 8;
                bf16x8 bhi = *(const bf16x8*)p, blo = *(const bf16x8*)(p + 512);
                acc = MFMA(nhi[kt], bhi, acc);
                acc = MFMA(nlo[kt], bhi, acc);
                acc = MFMA(nhi[kt], blo, acc);
            }
            int col = ntw * 16 + n0;
            float nb1 = node_b1[l * HH + col];
#pragma unroll
            for (int q = 0; q < 4; ++q) {
                int m = mtile * 16 + kg * 4 + q;
                if (m < PP) {
                    float v = silu_f(acc[q] + nb1);
                    unsigned short hi = f2bf(v);
                    unsigned short lo = f2bf(v - bf2f(hi));
                    sM[m * EST + col] = (unsigned)hi | ((unsigned)lo << 16);
                }
            }
        }
        __syncthreads();  // (3)

        // ================= [F] node MLP stage 2, h/x update, cleanup ========
        {
            int node = mtile * 16 + n0;
            int crow = node < PP ? node : 0;
            bool vn = node < PP;
            bf16x8 mh[2], ml[2];
#pragma unroll
            for (int kt = 0; kt < 2; ++kt) {
                const unsigned int* p = &sM[crow * EST + kt * 32 + kg * 8];
                uint4 u0 = *(const uint4*)p;
                uint4 u1 = *(const uint4*)(p + 4);
                unsigned uu[8] = {u0.x, u0.y, u0.z, u0.w, u1.x, u1.y, u1.z, u1.w};
#pragma unroll
                for (int j8 = 0; j8 < 8; ++j8) {
                    unsigned uv = vn ? uu[j8] : 0u;
                    mh[kt][j8] = (short)(uv & 0xffffu);
                    ml[kt][j8] = (short)(uv >> 16);
                }
            }
            f32x4 acc = (f32x4){0.f,0.f,0.f,0.f};
#pragma unroll
            for (int kt = 0; kt < 2; ++kt) {
                const unsigned short* p = wfl + (7 * 8 + kt * 4 + ntw) * 1024 + lane * 8;
                bf16x8 bhi = *(const bf16x8*)p, blo = *(const bf16x8*)(p + 512);
                acc = MFMA(mh[kt], bhi, acc);
                acc = MFMA(ml[kt], bhi, acc);
                acc = MFMA(mh[kt], blo, acc);
            }
            int col = ntw * 16 + n0;
            float nb2 = node_b2[l * HH + col];
#pragma unroll
            for (int q = 0; q < 4; ++q) {
                int m = mtile * 16 + kg * 4 + q;
                if (m < PP) sh[m][col] += acc[q] + nb2;
            }
        }
        if (tid < PP * 4) {
            int p = tid >> 2, d = tid & 3;
            float v = sTr[p][d];
            if (d < 3) sx[p][d] += v;
            sTr[p][d] = 0.f;
        }
        for (int idx = tid; idx < PP * SST; idx += 512) (&sSeg[0][0])[idx] = 0.f;
        __syncthreads();  // (4)
    }

    // ---- output: vel = (x - x0) - mean_p(x - x0) ----
    if (tid < 3) {
        float s = 0.0f;
        for (int p = 0; p < PP; ++p) s += sx[p][tid] - sx0[p][tid];
        smean[tid] = s / (float)PP;
    }
    __syncthreads();
    if (tid < PP * 3) {
        int p = tid / 3, d = tid % 3;
        out[g * (PP * 3) + tid] = (sx[p][d] - sx0[p][d]) - smean[d];
    }
}

extern "C" void kernel_launch(void* const* d_in, const int* in_sizes, int n_in,
                              void* d_out, int out_size, void* d_ws, size_t ws_size,
                              hipStream_t stream) {
    const float* input   = (const float*)d_in[0];
    const float* timev   = (const float*)d_in[1];
    const float* emb_w   = (const float*)d_in[2];
    const float* emb_b   = (const float*)d_in[3];
    const float* edge_w1 = (const float*)d_in[4];
    const float* edge_b1 = (const float*)d_in[5];
    const float* edge_w2 = (const float*)d_in[6];
    const float* edge_b2 = (const float*)d_in[7];
    const float* node_w1 = (const float*)d_in[8];
    const float* node_b1 = (const float*)d_in[9];
    const float* node_w2 = (const float*)d_in[10];
    const float* node_b2 = (const float*)d_in[11];
    const float* cm_w1   = (const float*)d_in[12];
    const float* cm_b1   = (const float*)d_in[13];
    const float* cm_w2   = (const float*)d_in[14];
    const float* cc_w1   = (const float*)d_in[15];
    const float* cc_b1   = (const float*)d_in[16];
    const float* cc_w2   = (const float*)d_in[17];
    // d_in[18]=row, d_in[19]=col: deterministic fully-connected edges, recomputed in-kernel

    unsigned short* wsu = (unsigned short*)d_ws;
    prep_w<<<dim3(256), dim3(64), 0, stream>>>(edge_w1, edge_w2, cm_w1, cc_w1,
                                               node_w1, node_w2, wsu);

    float* out = (float*)d_out;
    egnn_kernel<<<dim3(1024), dim3(512), 0, stream>>>(
        input, timev, emb_w, emb_b, edge_w1, edge_b1, edge_b2,
        node_b1, node_b2, cm_b1, cm_w2, cc_b1, cc_w2, wsu, out);
}

// Round 4
// 1196.097 us; speedup vs baseline: 1.1424x; 1.1424x over previous
//
#include <hip/hip_runtime.h>
#include <math.h>

#define PP 22
#define HH 64
#define NL 4
#define NE 462     // 22*21 directed edges
#define NTILE 29   // ceil(462/16) edge tiles of M=16
#define SST 68     // float stride for node-feature rows (bank-decorrelated)
#define EST 68     // uint stride for packed bf16 hi|lo tiles (68: 2-way max, 16B-aligned rows)

typedef __attribute__((ext_vector_type(8))) short bf16x8;
typedef __attribute__((ext_vector_type(4))) float f32x4;

#define MFMA(A, B, C) __builtin_amdgcn_mfma_f32_16x16x32_bf16(A, B, C, 0, 0, 0)

__device__ __forceinline__ float silu_f(float v) { return v / (1.0f + __expf(-v)); }

__device__ __forceinline__ unsigned short f2bf(float x) {
    unsigned int u = __float_as_uint(x);
    u += 0x7fffu + ((u >> 16) & 1u);
    return (unsigned short)(u >> 16);
}
__device__ __forceinline__ float bf2f(unsigned short h) {
    return __uint_as_float(((unsigned int)h) << 16);
}

#define LD8(dst, PTR) { \
    float4 _a = *(const float4*)(PTR); float4 _b = *(const float4*)((PTR) + 4); \
    dst[0]=_a.x; dst[1]=_a.y; dst[2]=_a.z; dst[3]=_a.w; \
    dst[4]=_b.x; dst[5]=_b.y; dst[6]=_b.z; dst[7]=_b.w; }

// ---------------------------------------------------------------------------
// Weight prep: 8 mats per layer -> hi/lo bf16 B-fragment blocks.
// mat: 0=W1a 1=W1b 2=W2 3=CM1 4=CC1 5=NW1a 6=NW1b 7=NW2
// block = ((l*8+mat)*2+kt)*4+nt, 1024 ushorts: [0..511] hi, [512..1023] lo
// frag element: lane*8+j -> M[kt*32+(lane>>4)*8+j][nt*16+(lane&15)]
// ---------------------------------------------------------------------------
__global__ __launch_bounds__(64) void prep_w(
    const float* __restrict__ edge_w1, const float* __restrict__ edge_w2,
    const float* __restrict__ cm_w1, const float* __restrict__ cc_w1,
    const float* __restrict__ node_w1, const float* __restrict__ node_w2,
    unsigned short* __restrict__ ws)
{
    int blk = blockIdx.x;
    int nt = blk & 3, kt = (blk >> 2) & 1, mat = (blk >> 3) & 7, l = blk >> 6;
    const float* src;
    switch (mat) {
        case 0: src = edge_w1 + l * 130 * HH; break;
        case 1: src = edge_w1 + l * 130 * HH + 64 * HH; break;
        case 2: src = edge_w2 + l * HH * HH; break;
        case 3: src = cm_w1   + l * HH * HH; break;
        case 4: src = cc_w1   + l * HH * HH; break;
        case 5: src = node_w1 + l * 128 * HH; break;
        case 6: src = node_w1 + l * 128 * HH + 64 * HH; break;
        default: src = node_w2 + l * HH * HH; break;
    }
    int lane = threadIdx.x;
    int n  = nt * 16 + (lane & 15);
    int kb = kt * 32 + (lane >> 4) * 8;
    unsigned short* dh = ws + blk * 1024 + lane * 8;
#pragma unroll
    for (int j = 0; j < 8; ++j) {
        float v = src[(kb + j) * HH + n];
        unsigned short hi = f2bf(v);
        unsigned short lo = f2bf(v - bf2f(hi));
        dh[j]       = hi;
        dh[512 + j] = lo;
    }
}

// ---------------------------------------------------------------------------
// Main kernel: one graph per block, 512 threads (8 waves), ~75KB LDS.
// launch_bounds(512,2): 256-reg unified budget -> no spills (R3's (512,4)
// capped at 128 and spilled 1.6GB of scratch; that was the whole regression).
// ---------------------------------------------------------------------------
__global__ __launch_bounds__(512, 2) void egnn_kernel(
    const float* __restrict__ input, const float* __restrict__ timev,
    const float* __restrict__ emb_w, const float* __restrict__ emb_b,
    const float* __restrict__ edge_w1, const float* __restrict__ edge_b1,
    const float* __restrict__ edge_b2,
    const float* __restrict__ node_b1, const float* __restrict__ node_b2,
    const float* __restrict__ cm_b1, const float* __restrict__ cm_w2,
    const float* __restrict__ cc_b1, const float* __restrict__ cc_w2,
    const unsigned short* __restrict__ wfr,
    float* __restrict__ out)
{
    const int g    = blockIdx.x;
    const int tid  = threadIdx.x;
    const int w    = tid >> 6;
    const int lane = tid & 63;
    const int n0   = lane & 15;
    const int kg   = lane >> 4;
    const int mtile = w >> 2;      // node-phase combo: M-tile 0/1
    const int ntw   = w & 3;       // node-phase combo: N-tile 0..3

    __shared__ float sApre[PP][SST], sBpre[PP][SST];
    __shared__ float sh[PP][SST], sSeg[PP][SST];
    __shared__ float srad[NE], sea[NE];
    __shared__ float scd[NE][3], scr[NE][3];
    __shared__ float sx[PP][3], sx0[PP][3], sTr[PP][4];
    __shared__ float sW128[HH], sW129[HH];
    __shared__ float smean[3];
    __shared__ __align__(16) unsigned int sEF[8][16 * EST];   // per-wave packed tiles
    unsigned int* sM = &sEF[0][0];                            // aliased in node phase

    // ---- init ----
    if (tid < PP * 3) {
        float v = input[g * (PP * 3) + tid];
        sx0[tid / 3][tid % 3] = v;
        sx [tid / 3][tid % 3] = v;
    }
    {
        float tg = timev[g];
        for (int i = w; i < PP; i += 8)
            sh[i][lane] = emb_w[i * HH + lane] + tg * emb_w[PP * HH + lane] + emb_b[lane];
    }
    for (int idx = tid; idx < PP * SST; idx += 512) (&sSeg[0][0])[idx] = 0.f;
    if (tid < PP * 4) (&sTr[0][0])[tid] = 0.f;
    __syncthreads();
    if (tid < NE) {
        int a = tid / 21, r = tid % 21;
        int b = (r < a) ? r : r + 1;
        float dx = sx0[a][0] - sx0[b][0];
        float dy = sx0[a][1] - sx0[b][1];
        float dz = sx0[a][2] - sx0[b][2];
        sea[tid] = dx * dx + dy * dy + dz * dz;
    }

    for (int l = 0; l < NL; ++l) {
        const unsigned short* wfl = wfr + (size_t)l * 65536;

        // ---- [A] geometry from current x ----
        if (tid < NE) {
            int a = tid / 21, r = tid % 21;
            int b = (r < a) ? r : r + 1;
            float ax = sx[a][0], ay = sx[a][1], az = sx[a][2];
            float bx = sx[b][0], by = sx[b][1], bz = sx[b][2];
            float dx = ax - bx, dy = ay - by, dz = az - bz;
            float rad = dx * dx + dy * dy + dz * dz;
            srad[tid] = rad;
            float inv = 1.0f / (sqrtf(rad + 1e-8f) + 1.0f);
            scd[tid][0] = dx * inv; scd[tid][1] = dy * inv; scd[tid][2] = dz * inv;
            float cx = ay * bz - az * by;
            float cy = az * bx - ax * bz;
            float cz = ax * by - ay * bx;
            float cn = 1.0f / (sqrtf(cx * cx + cy * cy + cz * cz + 1e-8f) + 1.0f);
            scr[tid][0] = cx * cn; scr[tid][1] = cy * cn; scr[tid][2] = cz * cn;
        }
        // ---- [B] W1 rows 128/129 ----
        if (tid < HH)          sW128[tid]      = edge_w1[(l * 130 + 128) * HH + tid];
        else if (tid < 2 * HH) sW129[tid - HH] = edge_w1[(l * 130 + 129) * HH + tid - HH];

        // ---- [C] Apre/Bpre via MFMA: combo (mtile, ntw) per wave ----
        {
            int node = mtile * 16 + n0;
            int crow = node < PP ? node : 0;
            bool vn = node < PP;
            bf16x8 hhi[2], hlo[2];
#pragma unroll
            for (int kt = 0; kt < 2; ++kt) {
                float vv[8];
                LD8(vv, &sh[crow][kt * 32 + kg * 8]);
#pragma unroll
                for (int j = 0; j < 8; ++j) {
                    float z = vn ? vv[j] : 0.f;
                    unsigned short hi = f2bf(z);
                    hhi[kt][j] = (short)hi;
                    hlo[kt][j] = (short)f2bf(z - bf2f(hi));
                }
            }
            f32x4 accA = (f32x4){0.f,0.f,0.f,0.f};
            f32x4 accB = (f32x4){0.f,0.f,0.f,0.f};
#pragma unroll
            for (int kt = 0; kt < 2; ++kt) {
                const unsigned short* p0 = wfl + (0 * 8 + kt * 4 + ntw) * 1024 + lane * 8;
                bf16x8 bhi = *(const bf16x8*)p0, blo = *(const bf16x8*)(p0 + 512);
                accA = MFMA(hhi[kt], bhi, accA);
                accA = MFMA(hlo[kt], bhi, accA);
                accA = MFMA(hhi[kt], blo, accA);
                const unsigned short* p1 = wfl + (1 * 8 + kt * 4 + ntw) * 1024 + lane * 8;
                bf16x8 chi = *(const bf16x8*)p1, clo = *(const bf16x8*)(p1 + 512);
                accB = MFMA(hhi[kt], chi, accB);
                accB = MFMA(hlo[kt], chi, accB);
                accB = MFMA(hhi[kt], clo, accB);
            }
            int col = ntw * 16 + n0;
            float b1v = edge_b1[l * HH + col];
#pragma unroll
            for (int q = 0; q < 4; ++q) {
                int m = mtile * 16 + kg * 4 + q;
                if (m < PP) {
                    sApre[m][col] = accA[q] + b1v;
                    sBpre[m][col] = accB[q];
                }
            }
        }
        // per-lane layer constants
        float b2r[4], cmbr[4], ccbr[4], cm2r[4], cc2r[4];
#pragma unroll
        for (int nt = 0; nt < 4; ++nt) {
            int idx = l * HH + nt * 16 + n0;
            b2r[nt]  = edge_b2[idx];
            cmbr[nt] = cm_b1[idx];
            ccbr[nt] = cc_b1[idx];
            cm2r[nt] = cm_w2[idx];
            cc2r[nt] = cc_w2[idx];
        }
        __syncthreads();  // (1)

        // ================= [D] edge phase: edge-major tiles =================
        unsigned int* sEFw = &sEF[w][0];
        for (int j = w; j < NTILE; j += 8) {
            int e0 = j * 16;
            int e = e0 + n0;
            int ec = e < NE ? e : 0;
            int a = ec / 21, r = ec - a * 21;
            int b = (r < a) ? r : r + 1;
            float radv = srad[ec], eav = sea[ec];

            // A-frags: z1 = silu(Apre[a]+Bpre[b]+rad*w128+ea*w129)
            bf16x8 ahi[2], alo[2];
#pragma unroll
            for (int kt = 0; kt < 2; ++kt) {
                int base = kt * 32 + kg * 8;
                float av[8], bv[8], w8[8], w9[8];
                LD8(av, &sApre[a][base]);
                LD8(bv, &sBpre[b][base]);
                LD8(w8, &sW128[base]);
                LD8(w9, &sW129[base]);
#pragma unroll
                for (int j8 = 0; j8 < 8; ++j8) {
                    float z = av[j8] + bv[j8] + radv * w8[j8] + eav * w9[j8];
                    z = silu_f(z);
                    unsigned short hi = f2bf(z);
                    ahi[kt][j8] = (short)hi;
                    alo[kt][j8] = (short)f2bf(z - bf2f(hi));
                }
            }

            // E2: EF = silu(z1@W2+b2); seg atomics; pack to sEFw
#pragma unroll
            for (int nt = 0; nt < 4; ++nt) {
                f32x4 acc = (f32x4){0.f,0.f,0.f,0.f};
#pragma unroll
                for (int kt = 0; kt < 2; ++kt) {
                    const unsigned short* p = wfl + (2 * 8 + kt * 4 + nt) * 1024 + lane * 8;
                    bf16x8 bhi = *(const bf16x8*)p, blo = *(const bf16x8*)(p + 512);
                    acc = MFMA(ahi[kt], bhi, acc);
                    acc = MFMA(alo[kt], bhi, acc);
                    acc = MFMA(ahi[kt], blo, acc);
                }
                int col = nt * 16 + n0;
#pragma unroll
                for (int q = 0; q < 4; ++q) {
                    int erow = kg * 4 + q;
                    int gE = e0 + erow;
                    bool vr = gE < NE;
                    float v = silu_f(acc[q] + b2r[nt]);
                    v = vr ? v : 0.f;
                    if (vr) {
                        int an = gE / 21;
                        atomicAdd(&sSeg[an][col], v);
                    }
                    unsigned short hi = f2bf(v);
                    unsigned short lo = f2bf(v - bf2f(hi));
                    sEFw[erow * EST + col] = (unsigned)hi | ((unsigned)lo << 16);
                }
            }

            // E3 A-frags from sEFw (per-wave ds ops are in-order)
            bf16x8 ehi[2], elo[2];
#pragma unroll
            for (int kt = 0; kt < 2; ++kt) {
                const unsigned int* p = &sEFw[n0 * EST + kt * 32 + kg * 8];
                uint4 u0 = *(const uint4*)p;
                uint4 u1 = *(const uint4*)(p + 4);
                unsigned uu[8] = {u0.x, u0.y, u0.z, u0.w, u1.x, u1.y, u1.z, u1.w};
#pragma unroll
                for (int j8 = 0; j8 < 8; ++j8) {
                    ehi[kt][j8] = (short)(uu[j8] & 0xffffu);
                    elo[kt][j8] = (short)(uu[j8] >> 16);
                }
            }

            // E3: cm/cc heads
            float pm[4] = {0.f,0.f,0.f,0.f}, pc[4] = {0.f,0.f,0.f,0.f};
#pragma unroll
            for (int nt = 0; nt < 4; ++nt) {
                f32x4 am = (f32x4){0.f,0.f,0.f,0.f};
                f32x4 ac = (f32x4){0.f,0.f,0.f,0.f};
#pragma unroll
                for (int kt = 0; kt < 2; ++kt) {
                    const unsigned short* pmw = wfl + (3 * 8 + kt * 4 + nt) * 1024 + lane * 8;
                    const unsigned short* pcw = wfl + (4 * 8 + kt * 4 + nt) * 1024 + lane * 8;
                    bf16x8 mhi = *(const bf16x8*)pmw, mlo = *(const bf16x8*)(pmw + 512);
                    bf16x8 chi = *(const bf16x8*)pcw, clo = *(const bf16x8*)(pcw + 512);
                    am = MFMA(ehi[kt], mhi, am);
                    am = MFMA(elo[kt], mhi, am);
                    am = MFMA(ehi[kt], mlo, am);
                    ac = MFMA(ehi[kt], chi, ac);
                    ac = MFMA(elo[kt], chi, ac);
                    ac = MFMA(ehi[kt], clo, ac);
                }
#pragma unroll
                for (int q = 0; q < 4; ++q) {
                    pm[q] += silu_f(am[q] + cmbr[nt]) * cm2r[nt];
                    pc[q] += silu_f(ac[q] + ccbr[nt]) * cc2r[nt];
                }
            }
#pragma unroll
            for (int q = 0; q < 4; ++q) {
#pragma unroll
                for (int off = 1; off <= 8; off <<= 1) {
                    pm[q] += __shfl_xor(pm[q], off);
                    pc[q] += __shfl_xor(pc[q], off);
                }
            }
            if (n0 < 3) {
#pragma unroll
                for (int q = 0; q < 4; ++q) {
                    int gE = e0 + kg * 4 + q;
                    if (gE < NE) {
                        int a2 = gE / 21;
                        atomicAdd(&sTr[a2][n0], scd[gE][n0] * pm[q] + pc[q] * scr[gE][n0]);
                    }
                }
            }
        }
        __syncthreads();  // (2)

        // ================= [E] node MLP stage 1 -> sM ======================
        {
            int node = mtile * 16 + n0;
            int crow = node < PP ? node : 0;
            bool vn = node < PP;
            bf16x8 nhi[4], nlo[4];
#pragma unroll
            for (int kt = 0; kt < 4; ++kt) {
                float vv[8];
                const float* src = (kt < 2) ? &sh[crow][kt * 32 + kg * 8]
                                            : &sSeg[crow][(kt - 2) * 32 + kg * 8];
                LD8(vv, src);
#pragma unroll
                for (int j8 = 0; j8 < 8; ++j8) {
                    float z = vn ? vv[j8] : 0.f;
                    unsigned short hi = f2bf(z);
                    nhi[kt][j8] = (short)hi;
                    nlo[kt][j8] = (short)f2bf(z - bf2f(hi));
                }
            }
            f32x4 acc = (f32x4){0.f,0.f,0.f,0.f};
#pragma unroll
            for (int kt = 0; kt < 4; ++kt) {
                int mat = (kt < 2) ? 5 : 6;
                int ktt = kt & 1;
                const unsigned short* p = wfl + (mat * 8 + ktt * 4 + ntw) * 1024 + lane * 8;
                bf16x8 bhi = *(const bf16x8*)p, blo = *(const bf16x8*)(p + 512);
                acc = MFMA(nhi[kt], bhi, acc);
                acc = MFMA(nlo[kt], bhi, acc);
                acc = MFMA(nhi[kt], blo, acc);
            }
            int col = ntw * 16 + n0;
            float nb1 = node_b1[l * HH + col];
#pragma unroll
            for (int q = 0; q < 4; ++q) {
                int m = mtile * 16 + kg * 4 + q;
                if (m < PP) {
                    float v = silu_f(acc[q] + nb1);
                    unsigned short hi = f2bf(v);
                    unsigned short lo = f2bf(v - bf2f(hi));
                    sM[m * EST + col] = (unsigned)hi | ((unsigned)lo << 16);
                }
            }
        }
        __syncthreads();  // (3)

        // ================= [F] node MLP stage 2, h/x update, cleanup ========
        {
            int node = mtile * 16 + n0;
            int crow = node < PP ? node : 0;
            bool vn = node < PP;
            bf16x8 mh[2], ml[2];
#pragma unroll
            for (int kt = 0; kt < 2; ++kt) {
                const unsigned int* p = &sM[crow * EST + kt * 32 + kg * 8];
                uint4 u0 = *(const uint4*)p;
                uint4 u1 = *(const uint4*)(p + 4);
                unsigned uu[8] = {u0.x, u0.y, u0.z, u0.w, u1.x, u1.y, u1.z, u1.w};
#pragma unroll
                for (int j8 = 0; j8 < 8; ++j8) {
                    unsigned uv = vn ? uu[j8] : 0u;
                    mh[kt][j8] = (short)(uv & 0xffffu);
                    ml[kt][j8] = (short)(uv >> 16);
                }
            }
            f32x4 acc = (f32x4){0.f,0.f,0.f,0.f};
#pragma unroll
            for (int kt = 0; kt < 2; ++kt) {
                const unsigned short* p = wfl + (7 * 8 + kt * 4 + ntw) * 1024 + lane * 8;
                bf16x8 bhi = *(const bf16x8*)p, blo = *(const bf16x8*)(p + 512);
                acc = MFMA(mh[kt], bhi, acc);
                acc = MFMA(ml[kt], bhi, acc);
                acc = MFMA(mh[kt], blo, acc);
            }
            int col = ntw * 16 + n0;
            float nb2 = node_b2[l * HH + col];
#pragma unroll
            for (int q = 0; q < 4; ++q) {
                int m = mtile * 16 + kg * 4 + q;
                if (m < PP) sh[m][col] += acc[q] + nb2;
            }
        }
        if (tid < PP * 4) {
            int p = tid >> 2, d = tid & 3;
            float v = sTr[p][d];
            if (d < 3) sx[p][d] += v;
            sTr[p][d] = 0.f;
        }
        for (int idx = tid; idx < PP * SST; idx += 512) (&sSeg[0][0])[idx] = 0.f;
        __syncthreads();  // (4)
    }

    // ---- output: vel = (x - x0) - mean_p(x - x0) ----
    if (tid < 3) {
        float s = 0.0f;
        for (int p = 0; p < PP; ++p) s += sx[p][tid] - sx0[p][tid];
        smean[tid] = s / (float)PP;
    }
    __syncthreads();
    if (tid < PP * 3) {
        int p = tid / 3, d = tid % 3;
        out[g * (PP * 3) + tid] = (sx[p][d] - sx0[p][d]) - smean[d];
    }
}

extern "C" void kernel_launch(void* const* d_in, const int* in_sizes, int n_in,
                              void* d_out, int out_size, void* d_ws, size_t ws_size,
                              hipStream_t stream) {
    const float* input   = (const float*)d_in[0];
    const float* timev   = (const float*)d_in[1];
    const float* emb_w   = (const float*)d_in[2];
    const float* emb_b   = (const float*)d_in[3];
    const float* edge_w1 = (const float*)d_in[4];
    const float* edge_b1 = (const float*)d_in[5];
    const float* edge_w2 = (const float*)d_in[6];
    const float* edge_b2 = (const float*)d_in[7];
    const float* node_w1 = (const float*)d_in[8];
    const float* node_b1 = (const float*)d_in[9];
    const float* node_w2 = (const float*)d_in[10];
    const float* node_b2 = (const float*)d_in[11];
    const float* cm_w1   = (const float*)d_in[12];
    const float* cm_b1   = (const float*)d_in[13];
    const float* cm_w2   = (const float*)d_in[14];
    const float* cc_w1   = (const float*)d_in[15];
    const float* cc_b1   = (const float*)d_in[16];
    const float* cc_w2   = (const float*)d_in[17];
    // d_in[18]=row, d_in[19]=col: deterministic fully-connected edges, recomputed in-kernel

    unsigned short* wsu = (unsigned short*)d_ws;
    prep_w<<<dim3(256), dim3(64), 0, stream>>>(edge_w1, edge_w2, cm_w1, cc_w1,
                                               node_w1, node_w2, wsu);

    float* out = (float*)d_out;
    egnn_kernel<<<dim3(1024), dim3(512), 0, stream>>>(
        input, timev, emb_w, emb_b, edge_w1, edge_b1, edge_b2,
        node_b1, node_b2, cm_b1, cm_w2, cc_b1, cc_w2, wsu, out);
}

// Round 5
// 1191.631 us; speedup vs baseline: 1.1467x; 1.0037x over previous
//
#include <hip/hip_runtime.h>
#include <math.h>

#define PP 22
#define HH 64
#define NL 4
#define NE 462     // 22*21 directed edges
#define NTILE 29   // ceil(462/16) edge tiles of M=16
#define SST 68     // float stride for node-feature rows (bank-decorrelated)
#define EST 68     // uint stride for packed bf16 hi|lo tiles

typedef __attribute__((ext_vector_type(8))) short bf16x8;
typedef __attribute__((ext_vector_type(4))) float f32x4;

#define MFMA(A, B, C) __builtin_amdgcn_mfma_f32_16x16x32_bf16(A, B, C, 0, 0, 0)

__device__ __forceinline__ float silu_f(float v) { return v / (1.0f + __expf(-v)); }

__device__ __forceinline__ unsigned short f2bf(float x) {
    unsigned int u = __float_as_uint(x);
    u += 0x7fffu + ((u >> 16) & 1u);
    return (unsigned short)(u >> 16);
}
__device__ __forceinline__ float bf2f(unsigned short h) {
    return __uint_as_float(((unsigned int)h) << 16);
}

#define LD8(dst, PTR) { \
    float4 _a = *(const float4*)(PTR); float4 _b = *(const float4*)((PTR) + 4); \
    dst[0]=_a.x; dst[1]=_a.y; dst[2]=_a.z; dst[3]=_a.w; \
    dst[4]=_b.x; dst[5]=_b.y; dst[6]=_b.z; dst[7]=_b.w; }

// ---------------------------------------------------------------------------
// Weight prep: 8 mats per layer -> hi/lo bf16 B-fragment blocks.
// mat: 0=W1a 1=W1b 2=W2 3=CM1 4=CC1 5=NW1a 6=NW1b 7=NW2
// block = ((l*8+mat)*2+kt)*4+nt, 1024 ushorts: [0..511] hi, [512..1023] lo
// frag element: lane*8+j -> M[kt*32+(lane>>4)*8+j][nt*16+(lane&15)]
// ---------------------------------------------------------------------------
__global__ __launch_bounds__(64) void prep_w(
    const float* __restrict__ edge_w1, const float* __restrict__ edge_w2,
    const float* __restrict__ cm_w1, const float* __restrict__ cc_w1,
    const float* __restrict__ node_w1, const float* __restrict__ node_w2,
    unsigned short* __restrict__ ws)
{
    int blk = blockIdx.x;
    int nt = blk & 3, kt = (blk >> 2) & 1, mat = (blk >> 3) & 7, l = blk >> 6;
    const float* src;
    switch (mat) {
        case 0: src = edge_w1 + l * 130 * HH; break;
        case 1: src = edge_w1 + l * 130 * HH + 64 * HH; break;
        case 2: src = edge_w2 + l * HH * HH; break;
        case 3: src = cm_w1   + l * HH * HH; break;
        case 4: src = cc_w1   + l * HH * HH; break;
        case 5: src = node_w1 + l * 128 * HH; break;
        case 6: src = node_w1 + l * 128 * HH + 64 * HH; break;
        default: src = node_w2 + l * HH * HH; break;
    }
    int lane = threadIdx.x;
    int n  = nt * 16 + (lane & 15);
    int kb = kt * 32 + (lane >> 4) * 8;
    unsigned short* dh = ws + blk * 1024 + lane * 8;
#pragma unroll
    for (int j = 0; j < 8; ++j) {
        float v = src[(kb + j) * HH + n];
        unsigned short hi = f2bf(v);
        unsigned short lo = f2bf(v - bf2f(hi));
        dh[j]       = hi;
        dh[512 + j] = lo;
    }
}

// ---------------------------------------------------------------------------
// Main kernel: one graph per block, 512 threads (8 waves), ~124KB LDS.
// Edge-phase weight frags (W2/CM1/CC1) are staged in LDS per layer: global
// frag loads in the unrolled inner loop caused ~32 hoisted dwordx4 loads ->
// VGPR blowout -> 0.9GB scratch spill (R4). ds_read frags sit at ~96 VGPR (R2).
// ---------------------------------------------------------------------------
__global__ __launch_bounds__(512, 2) void egnn_kernel(
    const float* __restrict__ input, const float* __restrict__ timev,
    const float* __restrict__ emb_w, const float* __restrict__ emb_b,
    const float* __restrict__ edge_w1, const float* __restrict__ edge_b1,
    const float* __restrict__ edge_b2,
    const float* __restrict__ node_b1, const float* __restrict__ node_b2,
    const float* __restrict__ cm_b1, const float* __restrict__ cm_w2,
    const float* __restrict__ cc_b1, const float* __restrict__ cc_w2,
    const unsigned short* __restrict__ wfr,
    float* __restrict__ out)
{
    const int g    = blockIdx.x;
    const int tid  = threadIdx.x;
    const int w    = tid >> 6;
    const int lane = tid & 63;
    const int n0   = lane & 15;
    const int kg   = lane >> 4;
    const int mtile = w >> 2;      // node-phase combo: M-tile 0/1
    const int ntw   = w & 3;       // node-phase combo: N-tile 0..3

    __shared__ __align__(16) unsigned short wlds[24 * 1024]; // 48KB: W2/CM1/CC1 frags
    __shared__ float sApre[PP][SST], sBpre[PP][SST];
    __shared__ float sh[PP][SST], sSeg[PP][SST];
    __shared__ float srad[NE], sea[NE];
    __shared__ float scd[NE][3], scr[NE][3];
    __shared__ float sx[PP][3], sx0[PP][3], sTr[PP][4];
    __shared__ float sW128[HH], sW129[HH];
    __shared__ float smean[3];
    __shared__ __align__(16) unsigned int sEF[8][16 * EST];   // per-wave packed tiles
    unsigned int* sM = &sEF[0][0];                            // aliased in node phase

    // ---- init ----
    if (tid < PP * 3) {
        float v = input[g * (PP * 3) + tid];
        sx0[tid / 3][tid % 3] = v;
        sx [tid / 3][tid % 3] = v;
    }
    {
        float tg = timev[g];
        for (int i = w; i < PP; i += 8)
            sh[i][lane] = emb_w[i * HH + lane] + tg * emb_w[PP * HH + lane] + emb_b[lane];
    }
    for (int idx = tid; idx < PP * SST; idx += 512) (&sSeg[0][0])[idx] = 0.f;
    if (tid < PP * 4) (&sTr[0][0])[tid] = 0.f;
    __syncthreads();
    if (tid < NE) {
        int a = tid / 21, r = tid % 21;
        int b = (r < a) ? r : r + 1;
        float dx = sx0[a][0] - sx0[b][0];
        float dy = sx0[a][1] - sx0[b][1];
        float dz = sx0[a][2] - sx0[b][2];
        sea[tid] = dx * dx + dy * dy + dz * dz;
    }

    for (int l = 0; l < NL; ++l) {
        const unsigned short* wfl = wfr + (size_t)l * 65536;

        // ---- stage W2/CM1/CC1 frag blocks (mats 2..4) into LDS ----
        {
            const uint4* src = (const uint4*)(wfl + 16 * 1024);
            uint4* dst = (uint4*)wlds;
            for (int idx = tid; idx < 3072; idx += 512) dst[idx] = src[idx];
        }

        // ---- [A] geometry from current x ----
        if (tid < NE) {
            int a = tid / 21, r = tid % 21;
            int b = (r < a) ? r : r + 1;
            float ax = sx[a][0], ay = sx[a][1], az = sx[a][2];
            float bx = sx[b][0], by = sx[b][1], bz = sx[b][2];
            float dx = ax - bx, dy = ay - by, dz = az - bz;
            float rad = dx * dx + dy * dy + dz * dz;
            srad[tid] = rad;
            float inv = 1.0f / (sqrtf(rad + 1e-8f) + 1.0f);
            scd[tid][0] = dx * inv; scd[tid][1] = dy * inv; scd[tid][2] = dz * inv;
            float cx = ay * bz - az * by;
            float cy = az * bx - ax * bz;
            float cz = ax * by - ay * bx;
            float cn = 1.0f / (sqrtf(cx * cx + cy * cy + cz * cz + 1e-8f) + 1.0f);
            scr[tid][0] = cx * cn; scr[tid][1] = cy * cn; scr[tid][2] = cz * cn;
        }
        // ---- [B] W1 rows 128/129 ----
        if (tid < HH)          sW128[tid]      = edge_w1[(l * 130 + 128) * HH + tid];
        else if (tid < 2 * HH) sW129[tid - HH] = edge_w1[(l * 130 + 129) * HH + tid - HH];

        // ---- [C] Apre/Bpre via MFMA: combo (mtile, ntw) per wave ----
        {
            int node = mtile * 16 + n0;
            int crow = node < PP ? node : 0;
            bool vn = node < PP;
            bf16x8 hhi[2], hlo[2];
#pragma unroll
            for (int kt = 0; kt < 2; ++kt) {
                float vv[8];
                LD8(vv, &sh[crow][kt * 32 + kg * 8]);
#pragma unroll
                for (int j = 0; j < 8; ++j) {
                    float z = vn ? vv[j] : 0.f;
                    unsigned short hi = f2bf(z);
                    hhi[kt][j] = (short)hi;
                    hlo[kt][j] = (short)f2bf(z - bf2f(hi));
                }
            }
            f32x4 accA = (f32x4){0.f,0.f,0.f,0.f};
            f32x4 accB = (f32x4){0.f,0.f,0.f,0.f};
#pragma unroll
            for (int kt = 0; kt < 2; ++kt) {
                const unsigned short* p0 = wfl + (0 * 8 + kt * 4 + ntw) * 1024 + lane * 8;
                bf16x8 bhi = *(const bf16x8*)p0, blo = *(const bf16x8*)(p0 + 512);
                accA = MFMA(hhi[kt], bhi, accA);
                accA = MFMA(hlo[kt], bhi, accA);
                accA = MFMA(hhi[kt], blo, accA);
                const unsigned short* p1 = wfl + (1 * 8 + kt * 4 + ntw) * 1024 + lane * 8;
                bf16x8 chi = *(const bf16x8*)p1, clo = *(const bf16x8*)(p1 + 512);
                accB = MFMA(hhi[kt], chi, accB);
                accB = MFMA(hlo[kt], chi, accB);
                accB = MFMA(hhi[kt], clo, accB);
            }
            int col = ntw * 16 + n0;
            float b1v = edge_b1[l * HH + col];
#pragma unroll
            for (int q = 0; q < 4; ++q) {
                int m = mtile * 16 + kg * 4 + q;
                if (m < PP) {
                    sApre[m][col] = accA[q] + b1v;
                    sBpre[m][col] = accB[q];
                }
            }
        }
        // per-lane layer constants
        float b2r[4], cmbr[4], ccbr[4], cm2r[4], cc2r[4];
#pragma unroll
        for (int nt = 0; nt < 4; ++nt) {
            int idx = l * HH + nt * 16 + n0;
            b2r[nt]  = edge_b2[idx];
            cmbr[nt] = cm_b1[idx];
            ccbr[nt] = cc_b1[idx];
            cm2r[nt] = cm_w2[idx];
            cc2r[nt] = cc_w2[idx];
        }
        __syncthreads();  // (1)

        // ================= [D] edge phase: edge-major tiles =================
        unsigned int* sEFw = &sEF[w][0];
        for (int j = w; j < NTILE; j += 8) {
            int e0 = j * 16;
            int e = e0 + n0;
            int ec = e < NE ? e : 0;
            int a = ec / 21, r = ec - a * 21;
            int b = (r < a) ? r : r + 1;
            float radv = srad[ec], eav = sea[ec];

            // A-frags: z1 = silu(Apre[a]+Bpre[b]+rad*w128+ea*w129)
            bf16x8 ahi[2], alo[2];
#pragma unroll
            for (int kt = 0; kt < 2; ++kt) {
                int base = kt * 32 + kg * 8;
                float av[8], bv[8], w8[8], w9[8];
                LD8(av, &sApre[a][base]);
                LD8(bv, &sBpre[b][base]);
                LD8(w8, &sW128[base]);
                LD8(w9, &sW129[base]);
#pragma unroll
                for (int j8 = 0; j8 < 8; ++j8) {
                    float z = av[j8] + bv[j8] + radv * w8[j8] + eav * w9[j8];
                    z = silu_f(z);
                    unsigned short hi = f2bf(z);
                    ahi[kt][j8] = (short)hi;
                    alo[kt][j8] = (short)f2bf(z - bf2f(hi));
                }
            }

            // E2: EF = silu(z1@W2+b2); seg atomics; pack to sEFw
#pragma unroll
            for (int nt = 0; nt < 4; ++nt) {
                f32x4 acc = (f32x4){0.f,0.f,0.f,0.f};
#pragma unroll
                for (int kt = 0; kt < 2; ++kt) {
                    const unsigned short* p = wlds + (kt * 4 + nt) * 1024 + lane * 8;
                    bf16x8 bhi = *(const bf16x8*)p, blo = *(const bf16x8*)(p + 512);
                    acc = MFMA(ahi[kt], bhi, acc);
                    acc = MFMA(alo[kt], bhi, acc);
                    acc = MFMA(ahi[kt], blo, acc);
                }
                int col = nt * 16 + n0;
#pragma unroll
                for (int q = 0; q < 4; ++q) {
                    int erow = kg * 4 + q;
                    int gE = e0 + erow;
                    bool vr = gE < NE;
                    float v = silu_f(acc[q] + b2r[nt]);
                    v = vr ? v : 0.f;
                    if (vr) {
                        int an = gE / 21;
                        atomicAdd(&sSeg[an][col], v);
                    }
                    unsigned short hi = f2bf(v);
                    unsigned short lo = f2bf(v - bf2f(hi));
                    sEFw[erow * EST + col] = (unsigned)hi | ((unsigned)lo << 16);
                }
            }

            // E3 A-frags from sEFw (per-wave ds ops are in-order)
            bf16x8 ehi[2], elo[2];
#pragma unroll
            for (int kt = 0; kt < 2; ++kt) {
                const unsigned int* p = &sEFw[n0 * EST + kt * 32 + kg * 8];
                uint4 u0 = *(const uint4*)p;
                uint4 u1 = *(const uint4*)(p + 4);
                unsigned uu[8] = {u0.x, u0.y, u0.z, u0.w, u1.x, u1.y, u1.z, u1.w};
#pragma unroll
                for (int j8 = 0; j8 < 8; ++j8) {
                    ehi[kt][j8] = (short)(uu[j8] & 0xffffu);
                    elo[kt][j8] = (short)(uu[j8] >> 16);
                }
            }

            // E3: cm/cc heads
            float pm[4] = {0.f,0.f,0.f,0.f}, pc[4] = {0.f,0.f,0.f,0.f};
#pragma unroll
            for (int nt = 0; nt < 4; ++nt) {
                f32x4 am = (f32x4){0.f,0.f,0.f,0.f};
                f32x4 ac = (f32x4){0.f,0.f,0.f,0.f};
#pragma unroll
                for (int kt = 0; kt < 2; ++kt) {
                    const unsigned short* pmw = wlds + (8 + kt * 4 + nt) * 1024 + lane * 8;
                    const unsigned short* pcw = wlds + (16 + kt * 4 + nt) * 1024 + lane * 8;
                    bf16x8 mhi = *(const bf16x8*)pmw, mlo = *(const bf16x8*)(pmw + 512);
                    bf16x8 chi = *(const bf16x8*)pcw, clo = *(const bf16x8*)(pcw + 512);
                    am = MFMA(ehi[kt], mhi, am);
                    am = MFMA(elo[kt], mhi, am);
                    am = MFMA(ehi[kt], mlo, am);
                    ac = MFMA(ehi[kt], chi, ac);
                    ac = MFMA(elo[kt], chi, ac);
                    ac = MFMA(ehi[kt], clo, ac);
                }
#pragma unroll
                for (int q = 0; q < 4; ++q) {
                    pm[q] += silu_f(am[q] + cmbr[nt]) * cm2r[nt];
                    pc[q] += silu_f(ac[q] + ccbr[nt]) * cc2r[nt];
                }
            }
#pragma unroll
            for (int q = 0; q < 4; ++q) {
#pragma unroll
                for (int off = 1; off <= 8; off <<= 1) {
                    pm[q] += __shfl_xor(pm[q], off);
                    pc[q] += __shfl_xor(pc[q], off);
                }
            }
            if (n0 < 3) {
#pragma unroll
                for (int q = 0; q < 4; ++q) {
                    int gE = e0 + kg * 4 + q;
                    if (gE < NE) {
                        int a2 = gE / 21;
                        atomicAdd(&sTr[a2][n0], scd[gE][n0] * pm[q] + pc[q] * scr[gE][n0]);
                    }
                }
            }
        }
        __syncthreads();  // (2)

        // ================= [E] node MLP stage 1 -> sM ======================
        {
            int node = mtile * 16 + n0;
            int crow = node < PP ? node : 0;
            bool vn = node < PP;
            bf16x8 nhi[4], nlo[4];
#pragma unroll
            for (int kt = 0; kt < 4; ++kt) {
                float vv[8];
                const float* src = (kt < 2) ? &sh[crow][kt * 32 + kg * 8]
                                            : &sSeg[crow][(kt - 2) * 32 + kg * 8];
                LD8(vv, src);
#pragma unroll
                for (int j8 = 0; j8 < 8; ++j8) {
                    float z = vn ? vv[j8] : 0.f;
                    unsigned short hi = f2bf(z);
                    nhi[kt][j8] = (short)hi;
                    nlo[kt][j8] = (short)f2bf(z - bf2f(hi));
                }
            }
            f32x4 acc = (f32x4){0.f,0.f,0.f,0.f};
#pragma unroll
            for (int kt = 0; kt < 4; ++kt) {
                int mat = (kt < 2) ? 5 : 6;
                int ktt = kt & 1;
                const unsigned short* p = wfl + (mat * 8 + ktt * 4 + ntw) * 1024 + lane * 8;
                bf16x8 bhi = *(const bf16x8*)p, blo = *(const bf16x8*)(p + 512);
                acc = MFMA(nhi[kt], bhi, acc);
                acc = MFMA(nlo[kt], bhi, acc);
                acc = MFMA(nhi[kt], blo, acc);
            }
            int col = ntw * 16 + n0;
            float nb1 = node_b1[l * HH + col];
#pragma unroll
            for (int q = 0; q < 4; ++q) {
                int m = mtile * 16 + kg * 4 + q;
                if (m < PP) {
                    float v = silu_f(acc[q] + nb1);
                    unsigned short hi = f2bf(v);
                    unsigned short lo = f2bf(v - bf2f(hi));
                    sM[m * EST + col] = (unsigned)hi | ((unsigned)lo << 16);
                }
            }
        }
        __syncthreads();  // (3)

        // ================= [F] node MLP stage 2, h/x update, cleanup ========
        {
            int node = mtile * 16 + n0;
            int crow = node < PP ? node : 0;
            bool vn = node < PP;
            bf16x8 mh[2], ml[2];
#pragma unroll
            for (int kt = 0; kt < 2; ++kt) {
                const unsigned int* p = &sM[crow * EST + kt * 32 + kg * 8];
                uint4 u0 = *(const uint4*)p;
                uint4 u1 = *(const uint4*)(p + 4);
                unsigned uu[8] = {u0.x, u0.y, u0.z, u0.w, u1.x, u1.y, u1.z, u1.w};
#pragma unroll
                for (int j8 = 0; j8 < 8; ++j8) {
                    unsigned uv = vn ? uu[j8] : 0u;
                    mh[kt][j8] = (short)(uv & 0xffffu);
                    ml[kt][j8] = (short)(uv >> 16);
                }
            }
            f32x4 acc = (f32x4){0.f,0.f,0.f,0.f};
#pragma unroll
            for (int kt = 0; kt < 2; ++kt) {
                const unsigned short* p = wfl + (7 * 8 + kt * 4 + ntw) * 1024 + lane * 8;
                bf16x8 bhi = *(const bf16x8*)p, blo = *(const bf16x8*)(p + 512);
                acc = MFMA(mh[kt], bhi, acc);
                acc = MFMA(ml[kt], bhi, acc);
                acc = MFMA(mh[kt], blo, acc);
            }
            int col = ntw * 16 + n0;
            float nb2 = node_b2[l * HH + col];
#pragma unroll
            for (int q = 0; q < 4; ++q) {
                int m = mtile * 16 + kg * 4 + q;
                if (m < PP) sh[m][col] += acc[q] + nb2;
            }
        }
        if (tid < PP * 4) {
            int p = tid >> 2, d = tid & 3;
            float v = sTr[p][d];
            if (d < 3) sx[p][d] += v;
            sTr[p][d] = 0.f;
        }
        for (int idx = tid; idx < PP * SST; idx += 512) (&sSeg[0][0])[idx] = 0.f;
        __syncthreads();  // (4)
    }

    // ---- output: vel = (x - x0) - mean_p(x - x0) ----
    if (tid < 3) {
        float s = 0.0f;
        for (int p = 0; p < PP; ++p) s += sx[p][tid] - sx0[p][tid];
        smean[tid] = s / (float)PP;
    }
    __syncthreads();
    if (tid < PP * 3) {
        int p = tid / 3, d = tid % 3;
        out[g * (PP * 3) + tid] = (sx[p][d] - sx0[p][d]) - smean[d];
    }
}

extern "C" void kernel_launch(void* const* d_in, const int* in_sizes, int n_in,
                              void* d_out, int out_size, void* d_ws, size_t ws_size,
                              hipStream_t stream) {
    const float* input   = (const float*)d_in[0];
    const float* timev   = (const float*)d_in[1];
    const float* emb_w   = (const float*)d_in[2];
    const float* emb_b   = (const float*)d_in[3];
    const float* edge_w1 = (const float*)d_in[4];
    const float* edge_b1 = (const float*)d_in[5];
    const float* edge_w2 = (const float*)d_in[6];
    const float* edge_b2 = (const float*)d_in[7];
    const float* node_w1 = (const float*)d_in[8];
    const float* node_b1 = (const float*)d_in[9];
    const float* node_w2 = (const float*)d_in[10];
    const float* node_b2 = (const float*)d_in[11];
    const float* cm_w1   = (const float*)d_in[12];
    const float* cm_b1   = (const float*)d_in[13];
    const float* cm_w2   = (const float*)d_in[14];
    const float* cc_w1   = (const float*)d_in[15];
    const float* cc_b1   = (const float*)d_in[16];
    const float* cc_w2   = (const float*)d_in[17];
    // d_in[18]=row, d_in[19]=col: deterministic fully-connected edges, recomputed in-kernel

    unsigned short* wsu = (unsigned short*)d_ws;
    prep_w<<<dim3(256), dim3(64), 0, stream>>>(edge_w1, edge_w2, cm_w1, cc_w1,
                                               node_w1, node_w2, wsu);

    float* out = (float*)d_out;
    egnn_kernel<<<dim3(1024), dim3(512), 0, stream>>>(
        input, timev, emb_w, emb_b, edge_w1, edge_b1, edge_b2,
        node_b1, node_b2, cm_b1, cm_w2, cc_b1, cc_w2, wsu, out);
}

// Round 6
// 1010.150 us; speedup vs baseline: 1.3527x; 1.1797x over previous
//
#include <hip/hip_runtime.h>
#include <math.h>

#define PP 22
#define HH 64
#define NL 4
#define NE 462     // 22*21 directed edges
#define NTILE 29   // ceil(462/16) edge tiles of M=16
#define SST 68     // float stride for node-feature rows

typedef __attribute__((ext_vector_type(8))) short bf16x8;
typedef __attribute__((ext_vector_type(4))) float f32x4;

#define MFMA(A, B, C) __builtin_amdgcn_mfma_f32_16x16x32_bf16(A, B, C, 0, 0, 0)
// feature permutation: C-frag row r of M-tile mt holds feature PHI(mt,r); chosen so
// lane (kg) ends up holding features kt*32+kg*8+j -> E3/stage2 A-frags are a pure
// register relabel of E2/stage1 C-frags (zero data movement between the GEMMs).
#define PHI(mt, r) ((((mt) >> 1) << 5) + (((r) >> 2) << 3) + (((mt) & 1) << 2) + ((r) & 3))

__device__ __forceinline__ float silu_f(float v) { return v / (1.0f + __expf(-v)); }

__device__ __forceinline__ unsigned short f2bf(float x) {
    unsigned int u = __float_as_uint(x);
    u += 0x7fffu + ((u >> 16) & 1u);
    return (unsigned short)(u >> 16);
}
__device__ __forceinline__ float bf2f(unsigned short h) {
    return __uint_as_float(((unsigned int)h) << 16);
}

#define LD8(dst, PTR) { \
    float4 _a = *(const float4*)(PTR); float4 _b = *(const float4*)((PTR) + 4); \
    dst[0]=_a.x; dst[1]=_a.y; dst[2]=_a.z; dst[3]=_a.w; \
    dst[4]=_b.x; dst[5]=_b.y; dst[6]=_b.z; dst[7]=_b.w; }

// ---------------------------------------------------------------------------
// Weight prep: hi-only bf16 frag blocks of 512 ushorts (lane*8+j).
// value = M[kt*32 + kg*8 + j][col]; col = nt*16+n0 (std B-layout) or PHI(mt,n0)
// (phi-permuted A-layout for the "swapped" GEMMs W2 / NW1).
// Per layer 64 blocks:
//  0-7  W1a std | 8-15 W1b std | 16-23 W2 phi | 24-31 CM1 std | 32-39 CC1 std
//  40-55 NW1 phi (kt=0..3, K=128) | 56-63 NW2 std
// ---------------------------------------------------------------------------
__global__ __launch_bounds__(64) void prep_w(
    const float* __restrict__ edge_w1, const float* __restrict__ edge_w2,
    const float* __restrict__ cm_w1, const float* __restrict__ cc_w1,
    const float* __restrict__ node_w1, const float* __restrict__ node_w2,
    unsigned short* __restrict__ ws)
{
    int blk = blockIdx.x;
    int l = blk >> 6, moff = blk & 63;
    int lane = threadIdx.x, n0 = lane & 15, kg = lane >> 4;
    const float* base; int col, kt;
    if (moff < 8)       { kt = moff >> 2;              int nt = moff & 3;        base = edge_w1 + l * 130 * HH;           col = nt * 16 + n0; }
    else if (moff < 16) { int m = moff - 8;  kt = m >> 2; int nt = m & 3;        base = edge_w1 + l * 130 * HH + 64 * HH; col = nt * 16 + n0; }
    else if (moff < 24) { int m = moff - 16; kt = m >> 2; int mt = m & 3;        base = edge_w2 + l * HH * HH;            col = PHI(mt, n0); }
    else if (moff < 32) { int m = moff - 24; kt = m >> 2; int nt = m & 3;        base = cm_w1 + l * HH * HH;              col = nt * 16 + n0; }
    else if (moff < 40) { int m = moff - 32; kt = m >> 2; int nt = m & 3;        base = cc_w1 + l * HH * HH;              col = nt * 16 + n0; }
    else if (moff < 56) { int m = moff - 40; kt = m >> 2; int mt = m & 3;        base = node_w1 + l * 128 * HH;           col = PHI(mt, n0); }
    else                { int m = moff - 56; kt = m >> 2; int nt = m & 3;        base = node_w2 + l * HH * HH;            col = nt * 16 + n0; }
    int k0 = kt * 32 + kg * 8;
    unsigned short* d = ws + blk * 512 + lane * 8;
#pragma unroll
    for (int j = 0; j < 8; ++j) d[j] = f2bf(base[(k0 + j) * HH + col]);
}

// ---------------------------------------------------------------------------
// Main kernel: one graph per block, 256 threads (4 waves), ~38KB LDS,
// launch_bounds(256,4) -> 4 blocks/CU, 16 waves/CU.
// ---------------------------------------------------------------------------
__global__ __launch_bounds__(256, 4) void egnn_kernel(
    const float* __restrict__ input, const float* __restrict__ timev,
    const float* __restrict__ emb_w, const float* __restrict__ emb_b,
    const float* __restrict__ edge_w1, const float* __restrict__ edge_b1,
    const float* __restrict__ edge_b2,
    const float* __restrict__ node_b1, const float* __restrict__ node_b2,
    const float* __restrict__ cm_b1, const float* __restrict__ cm_w2,
    const float* __restrict__ cc_b1, const float* __restrict__ cc_w2,
    const unsigned short* __restrict__ wfr,
    float* __restrict__ out)
{
    const int g    = blockIdx.x;
    const int tid  = threadIdx.x;
    const int w    = tid >> 6;     // wave 0..3
    const int lane = tid & 63;
    const int n0   = lane & 15;
    const int kg   = lane >> 4;

    __shared__ float sApre[PP][SST], sBpre[PP][SST];
    __shared__ float sh[PP][SST], sSeg[PP][SST];
    __shared__ float scd[NE][3], scr[NE][3];
    __shared__ float sx[PP][3], sx0[PP][3], sTr[PP][4];
    __shared__ float sW128[HH], sW129[HH];
    __shared__ float sBp[128];    // [0..63] b2[PHI], [64..127] nb1[PHI]
    __shared__ float sHC[256];    // [0]cmb [64]ccb [128]cm2 [192]cc2 (std index)
    __shared__ float smean[3];

    // ---- init ----
    if (tid < PP * 3) {
        float v = input[g * (PP * 3) + tid];
        sx0[tid / 3][tid % 3] = v;
        sx [tid / 3][tid % 3] = v;
    }
    {
        float tg = timev[g];
        for (int i = w; i < PP; i += 4)
            sh[i][lane] = emb_w[i * HH + lane] + tg * emb_w[PP * HH + lane] + emb_b[lane];
    }
    for (int idx = tid; idx < PP * SST; idx += 256) (&sSeg[0][0])[idx] = 0.f;
    if (tid < PP * 4) (&sTr[0][0])[tid] = 0.f;
    __syncthreads();  // (a) init done

    for (int l = 0; l < NL; ++l) {
        const unsigned short* wfl = wfr + (size_t)l * 32768;

        // ===== section A: geometry, constants, Apre/Bpre ====================
        for (int e = tid; e < NE; e += 256) {
            int a = e / 21, r = e - a * 21;
            int b = (r < a) ? r : r + 1;
            float ax = sx[a][0], ay = sx[a][1], az = sx[a][2];
            float bx = sx[b][0], by = sx[b][1], bz = sx[b][2];
            float dx = ax - bx, dy = ay - by, dz = az - bz;
            float rad = dx * dx + dy * dy + dz * dz;
            float inv = 1.0f / (sqrtf(rad + 1e-8f) + 1.0f);
            scd[e][0] = dx * inv; scd[e][1] = dy * inv; scd[e][2] = dz * inv;
            float cx = ay * bz - az * by;
            float cy = az * bx - ax * bz;
            float cz = ax * by - ay * bx;
            float cn = 1.0f / (sqrtf(cx * cx + cy * cy + cz * cz + 1e-8f) + 1.0f);
            scr[e][0] = cx * cn; scr[e][1] = cy * cn; scr[e][2] = cz * cn;
        }
        if (tid < HH)          sW128[tid]      = edge_w1[(l * 130 + 128) * HH + tid];
        else if (tid < 2 * HH) sW129[tid - HH] = edge_w1[(l * 130 + 129) * HH + tid - HH];
        if (tid < 128) {
            int i = tid & 63, mt = i >> 4, r = i & 15;
            int phi = PHI(mt, r);
            sBp[tid] = (tid < 64) ? edge_b2[l * HH + phi] : node_b1[l * HH + phi];
        }
        {
            int i = tid & 63, arr = tid >> 6;
            const float* src = (arr == 0) ? cm_b1 : (arr == 1) ? cc_b1 : (arr == 2) ? cm_w2 : cc_w2;
            sHC[tid] = src[l * HH + i];
        }
        // ---- [C] Apre/Bpre (orig orientation): wave w: node-tile w&1, mat w>>1
        {
            int mtn = w & 1, mat = w >> 1;
            int node = mtn * 16 + n0;
            bool vn = node < PP;
            int crow = vn ? node : 0;
            bf16x8 hhi[2], hlo[2];
#pragma unroll
            for (int kt = 0; kt < 2; ++kt) {
                float vv[8];
                LD8(vv, &sh[crow][kt * 32 + kg * 8]);
#pragma unroll
                for (int j = 0; j < 8; ++j) {
                    float z = vn ? vv[j] : 0.f;
                    unsigned short hi = f2bf(z);
                    hhi[kt][j] = (short)hi;
                    hlo[kt][j] = (short)f2bf(z - bf2f(hi));
                }
            }
#pragma unroll 1
            for (int ntf = 0; ntf < 4; ++ntf) {
                f32x4 acc = (f32x4){0.f, 0.f, 0.f, 0.f};
#pragma unroll
                for (int kt = 0; kt < 2; ++kt) {
                    bf16x8 wv = *(const bf16x8*)(wfl + (mat * 8 + kt * 4 + ntf) * 512 + lane * 8);
                    acc = MFMA(hhi[kt], wv, acc);
                    acc = MFMA(hlo[kt], wv, acc);
                }
                int col = ntf * 16 + n0;
                float b1v = edge_b1[l * HH + col];
#pragma unroll
                for (int q = 0; q < 4; ++q) {
                    int m = mtn * 16 + kg * 4 + q;
                    if (m < PP) {
                        if (mat == 0) sApre[m][col] = acc[q] + b1v;
                        else          sBpre[m][col] = acc[q];
                    }
                }
            }
        }
        __syncthreads();  // (b)

        // ===== edge phase: 29 M=16 edge tiles over 4 waves ==================
        for (int jt = w; jt < NTILE; jt += 4) {
            int e0 = jt * 16;
            int e = e0 + n0;
            bool vr = e < NE;
            int ec = vr ? e : (NE - 1);
            int a = ec / 21, r = ec - a * 21;
            int b = (r < a) ? r : r + 1;
            // per-lane rad/ea recompute
            float dx = sx[a][0] - sx[b][0];
            float dy = sx[a][1] - sx[b][1];
            float dz = sx[a][2] - sx[b][2];
            float rad = dx * dx + dy * dy + dz * dz;
            float ex = sx0[a][0] - sx0[b][0];
            float ey = sx0[a][1] - sx0[b][1];
            float ez = sx0[a][2] - sx0[b][2];
            float ea = ex * ex + ey * ey + ez * ez;

            // ---- E2 (swapped, phi-permuted rows): EF^T tiles ----
            f32x4 acc[4];
#pragma unroll
            for (int mt = 0; mt < 4; ++mt) acc[mt] = (f32x4){0.f, 0.f, 0.f, 0.f};
#pragma unroll 1
            for (int kt = 0; kt < 2; ++kt) {
                int base = kt * 32 + kg * 8;
                float av[8], bv[8], w8[8], w9[8];
                LD8(av, &sApre[a][base]);
                LD8(bv, &sBpre[b][base]);
                LD8(w8, &sW128[base]);
                LD8(w9, &sW129[base]);
                bf16x8 zhi, zlo;
#pragma unroll
                for (int j8 = 0; j8 < 8; ++j8) {
                    float z = av[j8] + bv[j8] + rad * w8[j8] + ea * w9[j8];
                    z = silu_f(z);
                    unsigned short hi = f2bf(z);
                    zhi[j8] = (short)hi;
                    zlo[j8] = (short)f2bf(z - bf2f(hi));
                }
#pragma unroll
                for (int mt = 0; mt < 4; ++mt) {
                    bf16x8 wv = *(const bf16x8*)(wfl + (16 + kt * 4 + mt) * 512 + lane * 8);
                    acc[mt] = MFMA(wv, zhi, acc[mt]);
                    acc[mt] = MFMA(wv, zlo, acc[mt]);
                }
            }
            // epilogue: silu + bias, mask, seg atomics, pack hi|lo
            unsigned int pk[4][4];
#pragma unroll
            for (int mt = 0; mt < 4; ++mt) {
                int phib = ((mt >> 1) << 5) + (kg << 3) + ((mt & 1) << 2);
#pragma unroll
                for (int q = 0; q < 4; ++q) {
                    float v = silu_f(acc[mt][q] + sBp[mt * 16 + kg * 4 + q]);
                    v = vr ? v : 0.f;
                    unsigned short hi = f2bf(v);
                    unsigned short lo = f2bf(v - bf2f(hi));
                    pk[mt][q] = (unsigned)hi | ((unsigned)lo << 16);
                    if (vr) atomicAdd(&sSeg[a][phib + q], v);
                }
            }
            // ---- E3 A-frags: pure register relabel of pk ----
            bf16x8 ehi[2], elo[2];
#pragma unroll
            for (int kt = 0; kt < 2; ++kt) {
#pragma unroll
                for (int j8 = 0; j8 < 8; ++j8) {
                    unsigned u = pk[kt * 2 + (j8 >> 2)][j8 & 3];
                    ehi[kt][j8] = (short)(u & 0xffffu);
                    elo[kt][j8] = (short)(u >> 16);
                }
            }
            // ---- E3 (orig orientation): cm/cc heads ----
            float pm[4] = {0.f, 0.f, 0.f, 0.f}, pc[4] = {0.f, 0.f, 0.f, 0.f};
#pragma unroll 1
            for (int nt = 0; nt < 4; ++nt) {
                f32x4 am = (f32x4){0.f, 0.f, 0.f, 0.f};
                f32x4 ac = (f32x4){0.f, 0.f, 0.f, 0.f};
#pragma unroll
                for (int kt = 0; kt < 2; ++kt) {
                    bf16x8 cmw = *(const bf16x8*)(wfl + (24 + kt * 4 + nt) * 512 + lane * 8);
                    bf16x8 ccw = *(const bf16x8*)(wfl + (32 + kt * 4 + nt) * 512 + lane * 8);
                    am = MFMA(ehi[kt], cmw, am);
                    am = MFMA(elo[kt], cmw, am);
                    ac = MFMA(ehi[kt], ccw, ac);
                    ac = MFMA(elo[kt], ccw, ac);
                }
                float cmb = sHC[nt * 16 + n0];
                float ccb = sHC[64 + nt * 16 + n0];
                float cm2 = sHC[128 + nt * 16 + n0];
                float cc2 = sHC[192 + nt * 16 + n0];
#pragma unroll
                for (int q = 0; q < 4; ++q) {
                    pm[q] += silu_f(am[q] + cmb) * cm2;
                    pc[q] += silu_f(ac[q] + ccb) * cc2;
                }
            }
#pragma unroll
            for (int q = 0; q < 4; ++q) {
#pragma unroll
                for (int off = 1; off <= 8; off <<= 1) {
                    pm[q] += __shfl_xor(pm[q], off);
                    pc[q] += __shfl_xor(pc[q], off);
                }
            }
            if (n0 < 3) {
#pragma unroll
                for (int q = 0; q < 4; ++q) {
                    int gE = e0 + kg * 4 + q;
                    if (gE < NE) {
                        int a2 = gE / 21;
                        atomicAdd(&sTr[a2][n0], scd[gE][n0] * pm[q] + pc[q] * scr[gE][n0]);
                    }
                }
            }
        }
        __syncthreads();  // (c)

        // ===== node MLP stage 1 (swapped, phi rows): wave pair per node-tile =
        unsigned int pk[4][4];
        {
            int mtn = w >> 1;                    // waves 0,1 -> tile 0; 2,3 -> tile 1
            int node = mtn * 16 + n0;
            bool vn = node < PP;
            int crow = vn ? node : 0;
            f32x4 acc[4];
#pragma unroll
            for (int mt = 0; mt < 4; ++mt) acc[mt] = (f32x4){0.f, 0.f, 0.f, 0.f};
#pragma unroll 1
            for (int kt = 0; kt < 4; ++kt) {
                const float* srcp = (kt < 2) ? &sh[crow][kt * 32 + kg * 8]
                                             : &sSeg[crow][(kt - 2) * 32 + kg * 8];
                float vv[8];
                LD8(vv, srcp);
                bf16x8 bhi, blo;
#pragma unroll
                for (int j8 = 0; j8 < 8; ++j8) {
                    float z = vn ? vv[j8] : 0.f;
                    unsigned short hi = f2bf(z);
                    bhi[j8] = (short)hi;
                    blo[j8] = (short)f2bf(z - bf2f(hi));
                }
#pragma unroll
                for (int mt = 0; mt < 4; ++mt) {
                    bf16x8 wv = *(const bf16x8*)(wfl + (40 + kt * 4 + mt) * 512 + lane * 8);
                    acc[mt] = MFMA(wv, bhi, acc[mt]);
                    acc[mt] = MFMA(wv, blo, acc[mt]);
                }
            }
#pragma unroll
            for (int mt = 0; mt < 4; ++mt) {
#pragma unroll
                for (int q = 0; q < 4; ++q) {
                    float v = silu_f(acc[mt][q] + sBp[64 + mt * 16 + kg * 4 + q]);
                    unsigned short hi = f2bf(v);
                    unsigned short lo = f2bf(v - bf2f(hi));
                    pk[mt][q] = (unsigned)hi | ((unsigned)lo << 16);
                }
            }
        }
        __syncthreads();  // (d)

        // ===== node MLP stage 2 (orig) + h/x update + cleanup ===============
        {
            bf16x8 mh[2], ml[2];
#pragma unroll
            for (int kt = 0; kt < 2; ++kt) {
#pragma unroll
                for (int j8 = 0; j8 < 8; ++j8) {
                    unsigned u = pk[kt * 2 + (j8 >> 2)][j8 & 3];
                    mh[kt][j8] = (short)(u & 0xffffu);
                    ml[kt][j8] = (short)(u >> 16);
                }
            }
            int mtn = w >> 1;
#pragma unroll 1
            for (int t = 0; t < 2; ++t) {
                int ntf = (w & 1) * 2 + t;
                f32x4 acc = (f32x4){0.f, 0.f, 0.f, 0.f};
#pragma unroll
                for (int kt = 0; kt < 2; ++kt) {
                    bf16x8 wv = *(const bf16x8*)(wfl + (56 + kt * 4 + ntf) * 512 + lane * 8);
                    acc = MFMA(mh[kt], wv, acc);
                    acc = MFMA(ml[kt], wv, acc);
                }
                int col = ntf * 16 + n0;
                float nb2 = node_b2[l * HH + col];
#pragma unroll
                for (int q = 0; q < 4; ++q) {
                    int m = mtn * 16 + kg * 4 + q;
                    if (m < PP) sh[m][col] += acc[q] + nb2;
                }
            }
        }
        if (tid < PP * 4) {
            int p = tid >> 2, d = tid & 3;
            float v = sTr[p][d];
            if (d < 3) sx[p][d] += v;
            sTr[p][d] = 0.f;
        }
        for (int idx = tid; idx < PP * SST; idx += 256) (&sSeg[0][0])[idx] = 0.f;
        __syncthreads();  // (a) for next layer
    }

    // ---- output: vel = (x - x0) - mean_p(x - x0) ----
    if (tid < 3) {
        float s = 0.0f;
        for (int p = 0; p < PP; ++p) s += sx[p][tid] - sx0[p][tid];
        smean[tid] = s / (float)PP;
    }
    __syncthreads();
    if (tid < PP * 3) {
        int p = tid / 3, d = tid % 3;
        out[g * (PP * 3) + tid] = (sx[p][d] - sx0[p][d]) - smean[d];
    }
}

extern "C" void kernel_launch(void* const* d_in, const int* in_sizes, int n_in,
                              void* d_out, int out_size, void* d_ws, size_t ws_size,
                              hipStream_t stream) {
    const float* input   = (const float*)d_in[0];
    const float* timev   = (const float*)d_in[1];
    const float* emb_w   = (const float*)d_in[2];
    const float* emb_b   = (const float*)d_in[3];
    const float* edge_w1 = (const float*)d_in[4];
    const float* edge_b1 = (const float*)d_in[5];
    const float* edge_w2 = (const float*)d_in[6];
    const float* edge_b2 = (const float*)d_in[7];
    const float* node_w1 = (const float*)d_in[8];
    const float* node_b1 = (const float*)d_in[9];
    const float* node_w2 = (const float*)d_in[10];
    const float* node_b2 = (const float*)d_in[11];
    const float* cm_w1   = (const float*)d_in[12];
    const float* cm_b1   = (const float*)d_in[13];
    const float* cm_w2   = (const float*)d_in[14];
    const float* cc_w1   = (const float*)d_in[15];
    const float* cc_b1   = (const float*)d_in[16];
    const float* cc_w2   = (const float*)d_in[17];
    // d_in[18]=row, d_in[19]=col: deterministic fully-connected edges, recomputed in-kernel

    unsigned short* wsu = (unsigned short*)d_ws;
    prep_w<<<dim3(NL * 64), dim3(64), 0, stream>>>(edge_w1, edge_w2, cm_w1, cc_w1,
                                                   node_w1, node_w2, wsu);

    float* out = (float*)d_out;
    egnn_kernel<<<dim3(1024), dim3(256), 0, stream>>>(
        input, timev, emb_w, emb_b, edge_w1, edge_b1, edge_b2,
        node_b1, node_b2, cm_b1, cm_w2, cc_b1, cc_w2, wsu, out);
}

// Round 7
// 856.373 us; speedup vs baseline: 1.5956x; 1.1796x over previous
//
#include <hip/hip_runtime.h>
#include <hip/hip_bf16.h>
#include <math.h>

#define PP 22
#define HH 64
#define NL 4
#define NE 462     // 22*21 directed edges, enumerated r-major: e = r*22 + a
#define NTILE 29   // ceil(462/16)
#define SST 68     // float stride for node-feature rows

typedef __attribute__((ext_vector_type(8))) short bf16x8;
typedef __attribute__((ext_vector_type(4))) float f32x4;

#define MFMA(A, B, C) __builtin_amdgcn_mfma_f32_16x16x32_bf16(A, B, C, 0, 0, 0)
// feature permutation: C-frag row r of M-tile mt holds feature PHI(mt,r); chosen so
// E3/stage2 A-frags are a pure register relabel of E2/stage1 C-frags.
#define PHI(mt, r) ((((mt) >> 1) << 5) + (((r) >> 2) << 3) + (((mt) & 1) << 2) + ((r) & 3))

__device__ __forceinline__ float silu_f(float v) { return v / (1.0f + __expf(-v)); }

__device__ __forceinline__ unsigned short f2bf(float x) {
    __hip_bfloat16 h = __float2bfloat16(x);   // RNE; compiler emits HW cvt
    unsigned short u;
    __builtin_memcpy(&u, &h, 2);
    return u;
}
__device__ __forceinline__ float bf2f(unsigned short h) {
    return __uint_as_float(((unsigned int)h) << 16);
}

#define LD8(dst, PTR) { \
    float4 _a = *(const float4*)(PTR); float4 _b = *(const float4*)((PTR) + 4); \
    dst[0]=_a.x; dst[1]=_a.y; dst[2]=_a.z; dst[3]=_a.w; \
    dst[4]=_b.x; dst[5]=_b.y; dst[6]=_b.z; dst[7]=_b.w; }

// ---------------------------------------------------------------------------
// Weight prep (unchanged layout from R6): hi-only bf16 frag blocks, 512 ushorts.
//  0-7 W1a | 8-15 W1b | 16-23 W2 phi | 24-31 CM1 | 32-39 CC1 | 40-55 NW1 phi | 56-63 NW2
// ---------------------------------------------------------------------------
__global__ __launch_bounds__(64) void prep_w(
    const float* __restrict__ edge_w1, const float* __restrict__ edge_w2,
    const float* __restrict__ cm_w1, const float* __restrict__ cc_w1,
    const float* __restrict__ node_w1, const float* __restrict__ node_w2,
    unsigned short* __restrict__ ws)
{
    int blk = blockIdx.x;
    int l = blk >> 6, moff = blk & 63;
    int lane = threadIdx.x, n0 = lane & 15, kg = lane >> 4;
    const float* base; int col, kt;
    if (moff < 8)       { kt = moff >> 2;              int nt = moff & 3;        base = edge_w1 + l * 130 * HH;           col = nt * 16 + n0; }
    else if (moff < 16) { int m = moff - 8;  kt = m >> 2; int nt = m & 3;        base = edge_w1 + l * 130 * HH + 64 * HH; col = nt * 16 + n0; }
    else if (moff < 24) { int m = moff - 16; kt = m >> 2; int mt = m & 3;        base = edge_w2 + l * HH * HH;            col = PHI(mt, n0); }
    else if (moff < 32) { int m = moff - 24; kt = m >> 2; int nt = m & 3;        base = cm_w1 + l * HH * HH;              col = nt * 16 + n0; }
    else if (moff < 40) { int m = moff - 32; kt = m >> 2; int nt = m & 3;        base = cc_w1 + l * HH * HH;              col = nt * 16 + n0; }
    else if (moff < 56) { int m = moff - 40; kt = m >> 2; int mt = m & 3;        base = node_w1 + l * 128 * HH;           col = PHI(mt, n0); }
    else                { int m = moff - 56; kt = m >> 2; int nt = m & 3;        base = node_w2 + l * HH * HH;            col = nt * 16 + n0; }
    int k0 = kt * 32 + kg * 8;
    unsigned short* d = ws + blk * 512 + lane * 8;
#pragma unroll
    for (int j = 0; j < 8; ++j) d[j] = f2bf(base[(k0 + j) * HH + col]);
}

// ---------------------------------------------------------------------------
// Main kernel: one graph per block, 256 threads (4 waves), ~39KB LDS,
// launch_bounds(256,4) -> 4 blocks/CU (LDS-limited), VGPR budget 128.
// ---------------------------------------------------------------------------
__global__ __launch_bounds__(256, 4) void egnn_kernel(
    const float* __restrict__ input, const float* __restrict__ timev,
    const float* __restrict__ emb_w, const float* __restrict__ emb_b,
    const float* __restrict__ edge_w1, const float* __restrict__ edge_b1,
    const float* __restrict__ edge_b2,
    const float* __restrict__ node_b1, const float* __restrict__ node_b2,
    const float* __restrict__ cm_b1, const float* __restrict__ cm_w2,
    const float* __restrict__ cc_b1, const float* __restrict__ cc_w2,
    const unsigned short* __restrict__ wfr,
    float* __restrict__ out)
{
    const int g    = blockIdx.x;
    const int tid  = threadIdx.x;
    const int w    = tid >> 6;     // wave 0..3
    const int lane = tid & 63;
    const int n0   = lane & 15;
    const int kg   = lane >> 4;

    __shared__ float sApre[PP][SST], sBpre[PP][SST];
    __shared__ float sh[PP][SST], sSeg[PP][SST];
    __shared__ float scd[NE][3], scr[NE][3];
    __shared__ __align__(16) float sx[PP][4];
    __shared__ __align__(16) float sx0[PP][4];
    __shared__ float sTr[PP][4];
    __shared__ float sW128[HH], sW129[HH];
    __shared__ float sBp[128];    // [0..63] b2[PHI], [64..127] nb1[PHI]
    __shared__ float sHC[256];    // [0]cmb [64]ccb [128]cm2 [192]cc2
    __shared__ float smean[3];

    // ---- init ----
    if (tid < PP * 3) {
        float v = input[g * (PP * 3) + tid];
        sx0[tid / 3][tid % 3] = v;
        sx [tid / 3][tid % 3] = v;
    }
    if (tid < PP) { sx0[tid][3] = 0.f; sx[tid][3] = 0.f; }
    {
        float tg = timev[g];
        for (int i = w; i < PP; i += 4)
            sh[i][lane] = emb_w[i * HH + lane] + tg * emb_w[PP * HH + lane] + emb_b[lane];
    }
    for (int idx = tid; idx < PP * SST; idx += 256) (&sSeg[0][0])[idx] = 0.f;
    if (tid < PP * 4) (&sTr[0][0])[tid] = 0.f;
    __syncthreads();  // (a)

    for (int l = 0; l < NL; ++l) {
        const unsigned short* wfl = wfr + (size_t)l * 32768;

        // ===== section A: geometry (r-major enumeration), constants, Apre/Bpre
        for (int e = tid; e < NE; e += 256) {
            int a = e % PP, r = e / PP;           // r-major: 16 consecutive e -> 16 distinct nodes
            int b = (r < a) ? r : r + 1;
            float4 xa = *(const float4*)&sx[a][0];
            float4 xb = *(const float4*)&sx[b][0];
            float dx = xa.x - xb.x, dy = xa.y - xb.y, dz = xa.z - xb.z;
            float rad = dx * dx + dy * dy + dz * dz;
            float inv = 1.0f / (sqrtf(rad + 1e-8f) + 1.0f);
            scd[e][0] = dx * inv; scd[e][1] = dy * inv; scd[e][2] = dz * inv;
            float cx = xa.y * xb.z - xa.z * xb.y;
            float cy = xa.z * xb.x - xa.x * xb.z;
            float cz = xa.x * xb.y - xa.y * xb.x;
            float cn = 1.0f / (sqrtf(cx * cx + cy * cy + cz * cz + 1e-8f) + 1.0f);
            scr[e][0] = cx * cn; scr[e][1] = cy * cn; scr[e][2] = cz * cn;
        }
        if (tid < HH)          sW128[tid]      = edge_w1[(l * 130 + 128) * HH + tid];
        else if (tid < 2 * HH) sW129[tid - HH] = edge_w1[(l * 130 + 129) * HH + tid - HH];
        if (tid < 128) {
            int i = tid & 63, mt = i >> 4, r = i & 15;
            int phi = PHI(mt, r);
            sBp[tid] = (tid < 64) ? edge_b2[l * HH + phi] : node_b1[l * HH + phi];
        }
        {
            int i = tid & 63, arr = tid >> 6;
            const float* src = (arr == 0) ? cm_b1 : (arr == 1) ? cc_b1 : (arr == 2) ? cm_w2 : cc_w2;
            sHC[tid] = src[l * HH + i];
        }
        // ---- [C] Apre/Bpre: wave w -> node-tile w&1, mat w>>1 ----
        {
            int mtn = w & 1, mat = w >> 1;
            int node = mtn * 16 + n0;
            bool vn = node < PP;
            int crow = vn ? node : 0;
            bf16x8 hhi[2], hlo[2];
#pragma unroll
            for (int kt = 0; kt < 2; ++kt) {
                float vv[8];
                LD8(vv, &sh[crow][kt * 32 + kg * 8]);
#pragma unroll
                for (int j = 0; j < 8; ++j) {
                    float z = vn ? vv[j] : 0.f;
                    unsigned short hi = f2bf(z);
                    hhi[kt][j] = (short)hi;
                    hlo[kt][j] = (short)f2bf(z - bf2f(hi));
                }
            }
#pragma unroll
            for (int ntf = 0; ntf < 4; ++ntf) {
                f32x4 acc = (f32x4){0.f, 0.f, 0.f, 0.f};
#pragma unroll
                for (int kt = 0; kt < 2; ++kt) {
                    bf16x8 wv = *(const bf16x8*)(wfl + (mat * 8 + kt * 4 + ntf) * 512 + lane * 8);
                    acc = MFMA(hhi[kt], wv, acc);
                    acc = MFMA(hlo[kt], wv, acc);
                }
                int col = ntf * 16 + n0;
                float b1v = edge_b1[l * HH + col];
#pragma unroll
                for (int q = 0; q < 4; ++q) {
                    int m = mtn * 16 + kg * 4 + q;
                    if (m < PP) {
                        if (mat == 0) sApre[m][col] = acc[q] + b1v;
                        else          sBpre[m][col] = acc[q];
                    }
                }
            }
        }
        __syncthreads();  // (b)

        // ===== edge phase =====
        // hoist loop-invariant W128/W129 slices (32 regs)
        float w8r[16], w9r[16];
        LD8(w8r,     &sW128[kg * 8]);
        LD8((w8r+8), &sW128[32 + kg * 8]);
        LD8(w9r,     &sW129[kg * 8]);
        LD8((w9r+8), &sW129[32 + kg * 8]);

        for (int jt = w; jt < NTILE; jt += 4) {
            int e0 = jt * 16;
            int e = e0 + n0;
            bool vr = e < NE;
            int ec = vr ? e : (NE - 1);
            int a = ec % PP, r = ec / PP;
            int b = (r < a) ? r : r + 1;
            float4 xa = *(const float4*)&sx[a][0];
            float4 xb = *(const float4*)&sx[b][0];
            float4 oa = *(const float4*)&sx0[a][0];
            float4 ob = *(const float4*)&sx0[b][0];
            float dx = xa.x - xb.x, dy = xa.y - xb.y, dz = xa.z - xb.z;
            float rad = dx * dx + dy * dy + dz * dz;
            float ex = oa.x - ob.x, ey = oa.y - ob.y, ez = oa.z - ob.z;
            float ea = ex * ex + ey * ey + ez * ez;

            // ---- E2 (swapped, phi rows) ----
            f32x4 acc[4];
#pragma unroll
            for (int mt = 0; mt < 4; ++mt) acc[mt] = (f32x4){0.f, 0.f, 0.f, 0.f};
#pragma unroll
            for (int kt = 0; kt < 2; ++kt) {
                int base = kt * 32 + kg * 8;
                float av[8], bv[8];
                LD8(av, &sApre[a][base]);
                LD8(bv, &sBpre[b][base]);
                bf16x8 zhi, zlo;
#pragma unroll
                for (int j8 = 0; j8 < 8; ++j8) {
                    float z = av[j8] + bv[j8] + rad * w8r[kt * 8 + j8] + ea * w9r[kt * 8 + j8];
                    z = silu_f(z);
                    unsigned short hi = f2bf(z);
                    zhi[j8] = (short)hi;
                    zlo[j8] = (short)f2bf(z - bf2f(hi));
                }
#pragma unroll
                for (int mt = 0; mt < 4; ++mt) {
                    bf16x8 wv = *(const bf16x8*)(wfl + (16 + kt * 4 + mt) * 512 + lane * 8);
                    acc[mt] = MFMA(wv, zhi, acc[mt]);
                    acc[mt] = MFMA(wv, zlo, acc[mt]);
                }
            }
            // epilogue: silu+bias, mask, seg atomics (distinct rows now), pack
            unsigned int pk[4][4];
#pragma unroll
            for (int mt = 0; mt < 4; ++mt) {
                int phib = ((mt >> 1) << 5) + (kg << 3) + ((mt & 1) << 2);
#pragma unroll
                for (int q = 0; q < 4; ++q) {
                    float v = silu_f(acc[mt][q] + sBp[mt * 16 + kg * 4 + q]);
                    v = vr ? v : 0.f;
                    unsigned short hi = f2bf(v);
                    unsigned short lo = f2bf(v - bf2f(hi));
                    pk[mt][q] = (unsigned)hi | ((unsigned)lo << 16);
                    if (vr) atomicAdd(&sSeg[a][phib + q], v);
                }
            }
            // ---- E3 A-frags: register relabel ----
            bf16x8 ehi[2], elo[2];
#pragma unroll
            for (int kt = 0; kt < 2; ++kt) {
#pragma unroll
                for (int j8 = 0; j8 < 8; ++j8) {
                    unsigned u = pk[kt * 2 + (j8 >> 2)][j8 & 3];
                    ehi[kt][j8] = (short)(u & 0xffffu);
                    elo[kt][j8] = (short)(u >> 16);
                }
            }
            // ---- E3: cm/cc heads ----
            float pm[4] = {0.f, 0.f, 0.f, 0.f}, pc[4] = {0.f, 0.f, 0.f, 0.f};
#pragma unroll 2
            for (int nt = 0; nt < 4; ++nt) {
                f32x4 am = (f32x4){0.f, 0.f, 0.f, 0.f};
                f32x4 ac = (f32x4){0.f, 0.f, 0.f, 0.f};
#pragma unroll
                for (int kt = 0; kt < 2; ++kt) {
                    bf16x8 cmw = *(const bf16x8*)(wfl + (24 + kt * 4 + nt) * 512 + lane * 8);
                    bf16x8 ccw = *(const bf16x8*)(wfl + (32 + kt * 4 + nt) * 512 + lane * 8);
                    am = MFMA(ehi[kt], cmw, am);
                    am = MFMA(elo[kt], cmw, am);
                    ac = MFMA(ehi[kt], ccw, ac);
                    ac = MFMA(elo[kt], ccw, ac);
                }
                float cmb = sHC[nt * 16 + n0];
                float ccb = sHC[64 + nt * 16 + n0];
                float cm2 = sHC[128 + nt * 16 + n0];
                float cc2 = sHC[192 + nt * 16 + n0];
#pragma unroll
                for (int q = 0; q < 4; ++q) {
                    pm[q] += silu_f(am[q] + cmb) * cm2;
                    pc[q] += silu_f(ac[q] + ccb) * cc2;
                }
            }
#pragma unroll
            for (int q = 0; q < 4; ++q) {
#pragma unroll
                for (int off = 1; off <= 8; off <<= 1) {
                    pm[q] += __shfl_xor(pm[q], off);
                    pc[q] += __shfl_xor(pc[q], off);
                }
            }
            if (n0 < 3) {
#pragma unroll
                for (int q = 0; q < 4; ++q) {
                    int gE = e0 + kg * 4 + q;
                    if (gE < NE) {
                        int a2 = gE % PP;       // distinct per (kg,q)
                        atomicAdd(&sTr[a2][n0], scd[gE][n0] * pm[q] + pc[q] * scr[gE][n0]);
                    }
                }
            }
        }
        __syncthreads();  // (c)

        // ===== node MLP stage 1 (swapped, phi rows) =====
        unsigned int pk[4][4];
        {
            int mtn = w >> 1;
            int node = mtn * 16 + n0;
            bool vn = node < PP;
            int crow = vn ? node : 0;
            f32x4 acc[4];
#pragma unroll
            for (int mt = 0; mt < 4; ++mt) acc[mt] = (f32x4){0.f, 0.f, 0.f, 0.f};
#pragma unroll 2
            for (int kt = 0; kt < 4; ++kt) {
                const float* srcp = (kt < 2) ? &sh[crow][kt * 32 + kg * 8]
                                             : &sSeg[crow][(kt - 2) * 32 + kg * 8];
                float vv[8];
                LD8(vv, srcp);
                bf16x8 bhi, blo;
#pragma unroll
                for (int j8 = 0; j8 < 8; ++j8) {
                    float z = vn ? vv[j8] : 0.f;
                    unsigned short hi = f2bf(z);
                    bhi[j8] = (short)hi;
                    blo[j8] = (short)f2bf(z - bf2f(hi));
                }
#pragma unroll
                for (int mt = 0; mt < 4; ++mt) {
                    bf16x8 wv = *(const bf16x8*)(wfl + (40 + kt * 4 + mt) * 512 + lane * 8);
                    acc[mt] = MFMA(wv, bhi, acc[mt]);
                    acc[mt] = MFMA(wv, blo, acc[mt]);
                }
            }
#pragma unroll
            for (int mt = 0; mt < 4; ++mt) {
#pragma unroll
                for (int q = 0; q < 4; ++q) {
                    float v = silu_f(acc[mt][q] + sBp[64 + mt * 16 + kg * 4 + q]);
                    unsigned short hi = f2bf(v);
                    unsigned short lo = f2bf(v - bf2f(hi));
                    pk[mt][q] = (unsigned)hi | ((unsigned)lo << 16);
                }
            }
        }
        __syncthreads();  // (d)

        // ===== node MLP stage 2 + h/x update + cleanup =====
        {
            bf16x8 mh[2], ml[2];
#pragma unroll
            for (int kt = 0; kt < 2; ++kt) {
#pragma unroll
                for (int j8 = 0; j8 < 8; ++j8) {
                    unsigned u = pk[kt * 2 + (j8 >> 2)][j8 & 3];
                    mh[kt][j8] = (short)(u & 0xffffu);
                    ml[kt][j8] = (short)(u >> 16);
                }
            }
            int mtn = w >> 1;
#pragma unroll
            for (int t = 0; t < 2; ++t) {
                int ntf = (w & 1) * 2 + t;
                f32x4 acc = (f32x4){0.f, 0.f, 0.f, 0.f};
#pragma unroll
                for (int kt = 0; kt < 2; ++kt) {
                    bf16x8 wv = *(const bf16x8*)(wfl + (56 + kt * 4 + ntf) * 512 + lane * 8);
                    acc = MFMA(mh[kt], wv, acc);
                    acc = MFMA(ml[kt], wv, acc);
                }
                int col = ntf * 16 + n0;
                float nb2 = node_b2[l * HH + col];
#pragma unroll
                for (int q = 0; q < 4; ++q) {
                    int m = mtn * 16 + kg * 4 + q;
                    if (m < PP) sh[m][col] += acc[q] + nb2;
                }
            }
        }
        if (tid < PP * 4) {
            int p = tid >> 2, d = tid & 3;
            float v = sTr[p][d];
            if (d < 3) sx[p][d] += v;
            sTr[p][d] = 0.f;
        }
        for (int idx = tid; idx < PP * SST; idx += 256) (&sSeg[0][0])[idx] = 0.f;
        __syncthreads();  // (a) next layer
    }

    // ---- output: vel = (x - x0) - mean_p(x - x0) ----
    if (tid < 3) {
        float s = 0.0f;
        for (int p = 0; p < PP; ++p) s += sx[p][tid] - sx0[p][tid];
        smean[tid] = s / (float)PP;
    }
    __syncthreads();
    if (tid < PP * 3) {
        int p = tid / 3, d = tid % 3;
        out[g * (PP * 3) + tid] = (sx[p][d] - sx0[p][d]) - smean[d];
    }
}

extern "C" void kernel_launch(void* const* d_in, const int* in_sizes, int n_in,
                              void* d_out, int out_size, void* d_ws, size_t ws_size,
                              hipStream_t stream) {
    const float* input   = (const float*)d_in[0];
    const float* timev   = (const float*)d_in[1];
    const float* emb_w   = (const float*)d_in[2];
    const float* emb_b   = (const float*)d_in[3];
    const float* edge_w1 = (const float*)d_in[4];
    const float* edge_b1 = (const float*)d_in[5];
    const float* edge_w2 = (const float*)d_in[6];
    const float* edge_b2 = (const float*)d_in[7];
    const float* node_w1 = (const float*)d_in[8];
    const float* node_b1 = (const float*)d_in[9];
    const float* node_w2 = (const float*)d_in[10];
    const float* node_b2 = (const float*)d_in[11];
    const float* cm_w1   = (const float*)d_in[12];
    const float* cm_b1   = (const float*)d_in[13];
    const float* cm_w2   = (const float*)d_in[14];
    const float* cc_w1   = (const float*)d_in[15];
    const float* cc_b1   = (const float*)d_in[16];
    const float* cc_w2   = (const float*)d_in[17];
    // d_in[18]=row, d_in[19]=col: deterministic fully-connected edges, recomputed in-kernel

    unsigned short* wsu = (unsigned short*)d_ws;
    prep_w<<<dim3(NL * 64), dim3(64), 0, stream>>>(edge_w1, edge_w2, cm_w1, cc_w1,
                                                   node_w1, node_w2, wsu);

    float* out = (float*)d_out;
    egnn_kernel<<<dim3(1024), dim3(256), 0, stream>>>(
        input, timev, emb_w, emb_b, edge_w1, edge_b1, edge_b2,
        node_b1, node_b2, cm_b1, cm_w2, cc_b1, cc_w2, wsu, out);
}